// Round 1
// baseline (468.951 us; speedup 1.0000x reference)
//
#include <hip/hip_runtime.h>
#include <hip/hip_bf16.h>

#define NB 8
#define NS 4096
#define NE 2048
#define NL 64
#define NH 128
#define NM (NB*NS)

typedef unsigned short ushort_t;
typedef __attribute__((ext_vector_type(4))) float f32x4;
typedef __attribute__((ext_vector_type(8))) __bf16 bf16x8;
typedef __attribute__((ext_vector_type(8))) unsigned short u16x8;

__device__ __forceinline__ unsigned short f2bf(float f) {
    union { float f; unsigned u; } v; v.f = f;
    unsigned u = v.u + 0x7fffu + ((v.u >> 16) & 1u);
    return (unsigned short)(u >> 16);
}

// XOR swizzle for 128-byte-stride LDS tiles (G4: fixes 16/32-way ds_read_b128 conflicts)
__device__ __forceinline__ int swz(int row, int colbyte) {
    return (row * 128 + colbyte) ^ ((row & 7) << 4);
}

// ---------------------------------------------------------------------------
// prep: WcatT[128][2048] bf16.  rows 0..63  = W_dkv (latent proj, already [L][E])
//                               rows 64..127 = absorbed^T[l][e] = sum_h Wq[h][e]*Wk[h][l]
// ---------------------------------------------------------------------------
__global__ __launch_bounds__(256) void prep_kernel(
    const float* __restrict__ Wdkv, const float* __restrict__ Wk,
    const float* __restrict__ Wq, ushort_t* __restrict__ WcatT)
{
    __shared__ float wk[128 * 64];
    const int t = threadIdx.x;
    for (int i = t; i < 128 * 64; i += 256) wk[i] = Wk[i];
    __syncthreads();
    const int e = blockIdx.x * 256 + t;
    float acc[64];
    #pragma unroll
    for (int l = 0; l < 64; ++l) acc[l] = 0.f;
    for (int h = 0; h < 128; ++h) {
        float q = Wq[h * NE + e];
        #pragma unroll
        for (int l = 0; l < 64; ++l) acc[l] += q * wk[h * 64 + l];
    }
    for (int l = 0; l < 64; ++l) WcatT[(64 + l) * NE + e] = f2bf(acc[l]);
    for (int l = 0; l < 64; ++l) WcatT[l * NE + e] = f2bf(Wdkv[l * NE + e]);
}

// ---------------------------------------------------------------------------
// proj: Y[M,128] = x[M,2048] @ WcatT^T.  cols 0..63 -> latent (f32 out + bf16 K),
// cols 64..127 -> q_res (bf16).  BM=64, BN=128, BK=64, 4 waves (2x2), MFMA 16x16x32.
// ---------------------------------------------------------------------------
__global__ __launch_bounds__(256) void proj_kernel(
    const float* __restrict__ x, const ushort_t* __restrict__ WcatT,
    float* __restrict__ latent_out, ushort_t* __restrict__ k_bf,
    ushort_t* __restrict__ q_bf)
{
    __shared__ ushort_t As[64 * 64];
    __shared__ ushort_t Bs[128 * 64];
    const int tid = threadIdx.x;
    const int w = tid >> 6, lane = tid & 63, lg = lane >> 4, li = lane & 15;
    const int m0 = blockIdx.x * 64;
    const int wm = (w >> 1) * 32, wn = (w & 1) * 64;

    f32x4 acc[2][4];
    #pragma unroll
    for (int i = 0; i < 2; ++i)
        #pragma unroll
        for (int j = 0; j < 4; ++j) acc[i][j] = f32x4{0.f, 0.f, 0.f, 0.f};

    for (int ks = 0; ks < NE / 64; ++ks) {
        const int k0 = ks * 64;
        // stage A (x tile, f32 -> bf16, swizzled)
        #pragma unroll
        for (int p = 0; p < 2; ++p) {
            int row = (tid >> 3) + 32 * p;
            int c = tid & 7;
            const float* gp = x + (long)(m0 + row) * NE + k0 + c * 8;
            f32x4 a0 = *reinterpret_cast<const f32x4*>(gp);
            f32x4 a1 = *reinterpret_cast<const f32x4*>(gp + 4);
            u16x8 h;
            h[0] = f2bf(a0[0]); h[1] = f2bf(a0[1]); h[2] = f2bf(a0[2]); h[3] = f2bf(a0[3]);
            h[4] = f2bf(a1[0]); h[5] = f2bf(a1[1]); h[6] = f2bf(a1[2]); h[7] = f2bf(a1[3]);
            *reinterpret_cast<u16x8*>(reinterpret_cast<char*>(As) + swz(row, c * 16)) = h;
        }
        // stage B (WcatT rows, bf16, swizzled)
        #pragma unroll
        for (int p = 0; p < 4; ++p) {
            int row = (tid >> 3) + 32 * p;
            int c = tid & 7;
            u16x8 h = *reinterpret_cast<const u16x8*>(WcatT + (long)row * NE + k0 + c * 8);
            *reinterpret_cast<u16x8*>(reinterpret_cast<char*>(Bs) + swz(row, c * 16)) = h;
        }
        __syncthreads();
        #pragma unroll
        for (int c = 0; c < 2; ++c) {
            bf16x8 af[2], bfv[4];
            #pragma unroll
            for (int mf = 0; mf < 2; ++mf)
                af[mf] = *reinterpret_cast<const bf16x8*>(
                    reinterpret_cast<const char*>(As) + swz(wm + 16 * mf + li, c * 64 + lg * 16));
            #pragma unroll
            for (int nf = 0; nf < 4; ++nf)
                bfv[nf] = *reinterpret_cast<const bf16x8*>(
                    reinterpret_cast<const char*>(Bs) + swz(wn + 16 * nf + li, c * 64 + lg * 16));
            #pragma unroll
            for (int mf = 0; mf < 2; ++mf)
                #pragma unroll
                for (int nf = 0; nf < 4; ++nf)
                    acc[mf][nf] = __builtin_amdgcn_mfma_f32_16x16x32_bf16(
                        af[mf], bfv[nf], acc[mf][nf], 0, 0, 0);
        }
        __syncthreads();
    }
    // epilogue: D layout col = lane&15, row = 4*(lane>>4)+reg  [verified m89/m91]
    #pragma unroll
    for (int mf = 0; mf < 2; ++mf) {
        #pragma unroll
        for (int nf = 0; nf < 4; ++nf) {
            int col = wn + 16 * nf + li;
            #pragma unroll
            for (int r = 0; r < 4; ++r) {
                int row = m0 + wm + 16 * mf + 4 * lg + r;
                float v = acc[mf][nf][r];
                if (col < 64) {
                    latent_out[(long)row * NL + col] = v;
                    k_bf[(long)row * NL + col] = f2bf(v);
                } else {
                    q_bf[(long)row * NL + (col - 64)] = f2bf(v);
                }
            }
        }
    }
}

// ---------------------------------------------------------------------------
// v: v_bf[M,128] = latent[M,64] @ Wv^T  (bf16 out).  LDS padded +1 (bank fix).
// ---------------------------------------------------------------------------
__global__ __launch_bounds__(256) void v_kernel(
    const float* __restrict__ latent, const float* __restrict__ Wv,
    ushort_t* __restrict__ v_bf)
{
    __shared__ float wv[128 * 65];
    __shared__ float ls[32 * 65];
    const int t = threadIdx.x;
    const int m0 = blockIdx.x * 32;
    for (int i = t; i < 128 * 64; i += 256) wv[(i >> 6) * 65 + (i & 63)] = Wv[i];
    for (int i = t; i < 32 * 64; i += 256) ls[(i >> 6) * 65 + (i & 63)] = latent[(long)m0 * 64 + i];
    __syncthreads();
    const int ml = t >> 3, dv0 = (t & 7) * 16;
    float acc[16];
    #pragma unroll
    for (int j = 0; j < 16; ++j) acc[j] = 0.f;
    for (int l = 0; l < 64; ++l) {
        float f = ls[ml * 65 + l];
        #pragma unroll
        for (int j = 0; j < 16; ++j) acc[j] += f * wv[(dv0 + j) * 65 + l];
    }
    u16x8 o0, o1;
    #pragma unroll
    for (int j = 0; j < 8; ++j) { o0[j] = f2bf(acc[j]); o1[j] = f2bf(acc[8 + j]); }
    u16x8* dst = reinterpret_cast<u16x8*>(v_bf + (long)(m0 + ml) * NH + dv0);
    dst[0] = o0; dst[1] = o1;
}

// ---------------------------------------------------------------------------
// attn: causal flash attention. per batch: Q,K [S,64], V [S,128].
// Block = 64 q-rows (4 waves x 16), KV tile = 64. Swapped QK^T (S^T = K@Q^T)
// so lane owns q-row = lane&15 -> wave-parallel softmax via shfl_xor(16,32).
// P re-layout through per-wave LDS (swizzled) for the PV A-operand.
// ---------------------------------------------------------------------------
__global__ __launch_bounds__(256) void attn_kernel(
    const ushort_t* __restrict__ q_bf, const ushort_t* __restrict__ k_bf,
    const ushort_t* __restrict__ v_bf, float* __restrict__ out)
{
    __shared__ ushort_t Ks[64 * 64];
    __shared__ ushort_t Vts[128 * 64];
    __shared__ ushort_t Ps[4][16 * 64];
    const int tid = threadIdx.x;
    const int w = tid >> 6, lane = tid & 63, lg = lane >> 4, li = lane & 15;
    const int b = blockIdx.y;
    const int qt = (gridDim.x - 1) - blockIdx.x;  // heavy tiles launch first
    const int Q0 = qt * 64;
    const float scale = 0.08838834764831845f;     // 128^-0.5

    // Q fragments in registers (B-operand): lane holds Q[Q0+16w+li][c*32+lg*8+j]
    const long qrow = (long)b * NS + Q0 + 16 * w + li;
    bf16x8 qf[2];
    qf[0] = *reinterpret_cast<const bf16x8*>(q_bf + qrow * NL + 0 + lg * 8);
    qf[1] = *reinterpret_cast<const bf16x8*>(q_bf + qrow * NL + 32 + lg * 8);

    float m_r = -3.0e38f, l_r = 0.f;
    f32x4 oacc[8];
    #pragma unroll
    for (int n = 0; n < 8; ++n) oacc[n] = f32x4{0.f, 0.f, 0.f, 0.f};

    for (int t = 0; t <= qt; ++t) {
        const int kv0 = t * 64;
        // stage K tile [64 kv][64 l], swizzled
        #pragma unroll
        for (int p = 0; p < 2; ++p) {
            int idx = tid + 256 * p;
            int row = idx >> 3, c = idx & 7;
            u16x8 h = *reinterpret_cast<const u16x8*>(
                k_bf + ((long)b * NS + kv0 + row) * NL + c * 8);
            *reinterpret_cast<u16x8*>(reinterpret_cast<char*>(Ks) + swz(row, c * 16)) = h;
        }
        // stage V^T [128 dv][64 kv], swizzled (writes land 2-way = free)
        #pragma unroll
        for (int p = 0; p < 4; ++p) {
            int kv = tid & 63;
            int c = (tid >> 6) + 4 * p;
            u16x8 h = *reinterpret_cast<const u16x8*>(
                v_bf + ((long)b * NS + kv0 + kv) * NH + c * 8);
            #pragma unroll
            for (int i = 0; i < 8; ++i) {
                int dv = c * 8 + i;
                *reinterpret_cast<ushort_t*>(reinterpret_cast<char*>(Vts) +
                    ((dv * 128 + kv * 2) ^ ((dv & 7) << 4))) = h[i];
            }
        }
        __syncthreads();

        // S^T = K @ Q^T : lane holds col q=li, rows kv = 16f + 4lg + r
        f32x4 s[4];
        #pragma unroll
        for (int f = 0; f < 4; ++f) s[f] = f32x4{0.f, 0.f, 0.f, 0.f};
        #pragma unroll
        for (int c = 0; c < 2; ++c)
            #pragma unroll
            for (int f = 0; f < 4; ++f) {
                bf16x8 a = *reinterpret_cast<const bf16x8*>(
                    reinterpret_cast<const char*>(Ks) + swz(16 * f + li, c * 64 + lg * 16));
                s[f] = __builtin_amdgcn_mfma_f32_16x16x32_bf16(a, qf[c], s[f], 0, 0, 0);
            }

        // online softmax, lane owns q-row = li
        float p[16];
        float mx = -3.0e38f;
        const bool diag = (t == qt);
        #pragma unroll
        for (int f = 0; f < 4; ++f)
            #pragma unroll
            for (int r = 0; r < 4; ++r) {
                float v = s[f][r] * scale;
                if (diag && (16 * f + 4 * lg + r) > (16 * w + li)) v = -3.0e38f;
                p[f * 4 + r] = v;
                mx = fmaxf(mx, v);
            }
        mx = fmaxf(mx, __shfl_xor(mx, 16));
        mx = fmaxf(mx, __shfl_xor(mx, 32));
        float m_new = fmaxf(m_r, mx);
        float corr = __expf(m_r - m_new);
        float rs = 0.f;
        #pragma unroll
        for (int i = 0; i < 16; ++i) { p[i] = __expf(p[i] - m_new); rs += p[i]; }
        rs += __shfl_xor(rs, 16);
        rs += __shfl_xor(rs, 32);
        l_r = l_r * corr + rs;
        m_r = m_new;

        // write P[q=li][kv] bf16 pairs into per-wave LDS (swizzled)
        #pragma unroll
        for (int f = 0; f < 4; ++f)
            #pragma unroll
            for (int rp = 0; rp < 2; ++rp) {
                unsigned pk = (unsigned)f2bf(p[f * 4 + rp * 2]) |
                              ((unsigned)f2bf(p[f * 4 + rp * 2 + 1]) << 16);
                int kv = 16 * f + 4 * lg + rp * 2;
                *reinterpret_cast<unsigned*>(reinterpret_cast<char*>(Ps[w]) +
                    swz(li, kv * 2)) = pk;
            }

        // rescale O (O rows live at q = 4lg+r; state lives at lanes with li == q)
        float corrO[4];
        #pragma unroll
        for (int r = 0; r < 4; ++r)
            corrO[r] = __shfl(corr, (lane & 48) | (4 * lg + r));
        #pragma unroll
        for (int n = 0; n < 8; ++n)
            #pragma unroll
            for (int r = 0; r < 4; ++r) oacc[n][r] *= corrO[r];

        // O += P @ V
        #pragma unroll
        for (int c = 0; c < 2; ++c) {
            bf16x8 pa = *reinterpret_cast<const bf16x8*>(
                reinterpret_cast<const char*>(Ps[w]) + swz(li, c * 64 + lg * 16));
            #pragma unroll
            for (int n = 0; n < 8; ++n) {
                bf16x8 vb = *reinterpret_cast<const bf16x8*>(
                    reinterpret_cast<const char*>(Vts) + swz(16 * n + li, c * 64 + lg * 16));
                oacc[n] = __builtin_amdgcn_mfma_f32_16x16x32_bf16(pa, vb, oacc[n], 0, 0, 0);
            }
        }
        __syncthreads();
    }

    // epilogue: out[b, Q0+16w+4lg+r, 16n+li] = O / l
    float invl[4];
    #pragma unroll
    for (int r = 0; r < 4; ++r)
        invl[r] = __shfl(1.f / l_r, (lane & 48) | (4 * lg + r));
    #pragma unroll
    for (int n = 0; n < 8; ++n)
        #pragma unroll
        for (int r = 0; r < 4; ++r) {
            long row = (long)b * NS + Q0 + 16 * w + 4 * lg + r;
            out[row * NH + 16 * n + li] = oacc[n][r] * invl[r];
        }
}

// ---------------------------------------------------------------------------
extern "C" void kernel_launch(void* const* d_in, const int* in_sizes, int n_in,
                              void* d_out, int out_size, void* d_ws, size_t ws_size,
                              hipStream_t stream) {
    const float* x    = (const float*)d_in[0];
    const float* Wdkv = (const float*)d_in[1];
    const float* Wk   = (const float*)d_in[2];
    const float* Wv   = (const float*)d_in[3];
    const float* Wq   = (const float*)d_in[4];

    float* out = (float*)d_out;
    float* latent_out = out + (long)NM * NH;   // output 1 follows output 0

    // workspace layout (16.5 MB total)
    ushort_t* WcatT = (ushort_t*)d_ws;                 // 128*2048 bf16 = 512 KB
    ushort_t* q_bf  = WcatT + 128 * NE;                // M*64 bf16 = 4 MB
    ushort_t* k_bf  = q_bf + (long)NM * NL;            // 4 MB
    ushort_t* v_bf  = k_bf + (long)NM * NL;            // M*128 bf16 = 8 MB

    hipLaunchKernelGGL(prep_kernel, dim3(NE / 256), dim3(256), 0, stream, Wdkv, Wk, Wq, WcatT);
    hipLaunchKernelGGL(proj_kernel, dim3(NM / 64), dim3(256), 0, stream, x, WcatT, latent_out, k_bf, q_bf);
    hipLaunchKernelGGL(v_kernel, dim3(NM / 32), dim3(256), 0, stream, latent_out, Wv, v_bf);
    hipLaunchKernelGGL(attn_kernel, dim3(NS / 64, NB), dim3(256), 0, stream, q_bf, k_bf, v_bf, out);
}

// Round 2
// 282.181 us; speedup vs baseline: 1.6619x; 1.6619x over previous
//
#include <hip/hip_runtime.h>
#include <hip/hip_bf16.h>

#define NB 8
#define NS 4096
#define NE 2048
#define NL 64
#define NH 128
#define NM (NB*NS)

typedef unsigned short ushort_t;
typedef __attribute__((ext_vector_type(4))) float f32x4;
typedef __attribute__((ext_vector_type(8))) __bf16 bf16x8;
typedef __attribute__((ext_vector_type(8))) unsigned short u16x8;

__device__ __forceinline__ unsigned short f2bf(float f) {
    union { float f; unsigned u; } v; v.f = f;
    unsigned u = v.u + 0x7fffu + ((v.u >> 16) & 1u);
    return (unsigned short)(u >> 16);
}

// XOR swizzle for 128-byte-stride LDS tiles (G4: fixes 16/32-way ds_read_b128 conflicts)
__device__ __forceinline__ int swz(int row, int colbyte) {
    return (row * 128 + colbyte) ^ ((row & 7) << 4);
}

// ---------------------------------------------------------------------------
// prep: WcatT[128][2048] bf16.  rows 0..63  = W_dkv, rows 64..127 = absorbed^T
// ---------------------------------------------------------------------------
__global__ __launch_bounds__(256) void prep_kernel(
    const float* __restrict__ Wdkv, const float* __restrict__ Wk,
    const float* __restrict__ Wq, ushort_t* __restrict__ WcatT)
{
    __shared__ float wk[128 * 64];
    const int t = threadIdx.x;
    for (int i = t; i < 128 * 64; i += 256) wk[i] = Wk[i];
    __syncthreads();
    const int e = blockIdx.x * 256 + t;
    float acc[64];
    #pragma unroll
    for (int l = 0; l < 64; ++l) acc[l] = 0.f;
    for (int h = 0; h < 128; ++h) {
        float q = Wq[h * NE + e];
        #pragma unroll
        for (int l = 0; l < 64; ++l) acc[l] += q * wk[h * 64 + l];
    }
    for (int l = 0; l < 64; ++l) WcatT[(64 + l) * NE + e] = f2bf(acc[l]);
    for (int l = 0; l < 64; ++l) WcatT[l * NE + e] = f2bf(Wdkv[l * NE + e]);
}

// ---------------------------------------------------------------------------
// proj: Y[M,128] = x[M,2048] @ WcatT^T.  BM=64,BN=128,BK=64, 4 waves (2x2).
// Single-barrier software pipeline: issue loads(t+1) -> compute(t) -> write(t+1).
// ---------------------------------------------------------------------------
__global__ __launch_bounds__(256) void proj_kernel(
    const float* __restrict__ x, const ushort_t* __restrict__ WcatT,
    float* __restrict__ latent_out, ushort_t* __restrict__ k_bf,
    ushort_t* __restrict__ q_bf)
{
    __shared__ ushort_t As[2][64 * 64];
    __shared__ ushort_t Bs[2][128 * 64];
    const int tid = threadIdx.x;
    const int w = tid >> 6, lane = tid & 63, lg = lane >> 4, li = lane & 15;
    const int m0 = blockIdx.x * 64;
    const int wm = (w >> 1) * 32, wn = (w & 1) * 64;
    const int srow = tid >> 3, scol = tid & 7;

    f32x4 acc[2][4];
    #pragma unroll
    for (int i = 0; i < 2; ++i)
        #pragma unroll
        for (int j = 0; j < 4; ++j) acc[i][j] = f32x4{0.f, 0.f, 0.f, 0.f};

    f32x4 areg[2][2];
    u16x8 breg[4];

    auto load_tile = [&](int k0) {
        #pragma unroll
        for (int p = 0; p < 2; ++p) {
            const float* gp = x + (long)(m0 + srow + 32 * p) * NE + k0 + scol * 8;
            areg[p][0] = *reinterpret_cast<const f32x4*>(gp);
            areg[p][1] = *reinterpret_cast<const f32x4*>(gp + 4);
        }
        #pragma unroll
        for (int p = 0; p < 4; ++p)
            breg[p] = *reinterpret_cast<const u16x8*>(
                WcatT + (long)(srow + 32 * p) * NE + k0 + scol * 8);
    };
    auto write_tile = [&](int buf) {
        #pragma unroll
        for (int p = 0; p < 2; ++p) {
            u16x8 h;
            #pragma unroll
            for (int j = 0; j < 4; ++j) {
                h[j] = f2bf(areg[p][0][j]);
                h[4 + j] = f2bf(areg[p][1][j]);
            }
            *reinterpret_cast<u16x8*>(reinterpret_cast<char*>(As[buf]) +
                swz(srow + 32 * p, scol * 16)) = h;
        }
        #pragma unroll
        for (int p = 0; p < 4; ++p)
            *reinterpret_cast<u16x8*>(reinterpret_cast<char*>(Bs[buf]) +
                swz(srow + 32 * p, scol * 16)) = breg[p];
    };

    load_tile(0);
    write_tile(0);
    __syncthreads();

    for (int ks = 0; ks < NE / 64; ++ks) {
        const int cur = ks & 1;
        if (ks < NE / 64 - 1) load_tile((ks + 1) * 64);

        #pragma unroll
        for (int c = 0; c < 2; ++c) {
            bf16x8 af[2], bfv[4];
            #pragma unroll
            for (int mf = 0; mf < 2; ++mf)
                af[mf] = *reinterpret_cast<const bf16x8*>(
                    reinterpret_cast<const char*>(As[cur]) + swz(wm + 16 * mf + li, c * 64 + lg * 16));
            #pragma unroll
            for (int nf = 0; nf < 4; ++nf)
                bfv[nf] = *reinterpret_cast<const bf16x8*>(
                    reinterpret_cast<const char*>(Bs[cur]) + swz(wn + 16 * nf + li, c * 64 + lg * 16));
            #pragma unroll
            for (int mf = 0; mf < 2; ++mf)
                #pragma unroll
                for (int nf = 0; nf < 4; ++nf)
                    acc[mf][nf] = __builtin_amdgcn_mfma_f32_16x16x32_bf16(
                        af[mf], bfv[nf], acc[mf][nf], 0, 0, 0);
        }
        if (ks < NE / 64 - 1) write_tile(cur ^ 1);
        __syncthreads();
    }

    // epilogue: D layout col = lane&15, row = 4*(lane>>4)+reg
    #pragma unroll
    for (int mf = 0; mf < 2; ++mf) {
        #pragma unroll
        for (int nf = 0; nf < 4; ++nf) {
            int col = wn + 16 * nf + li;
            #pragma unroll
            for (int r = 0; r < 4; ++r) {
                int row = m0 + wm + 16 * mf + 4 * lg + r;
                float v = acc[mf][nf][r];
                if (col < 64) {
                    latent_out[(long)row * NL + col] = v;
                    k_bf[(long)row * NL + col] = f2bf(v);
                } else {
                    q_bf[(long)row * NL + (col - 64)] = f2bf(v);
                }
            }
        }
    }
}

// ---------------------------------------------------------------------------
// v: v_t[b][dv][s] = (latent[b,s,:] @ Wv^T) transposed, bf16.
// Transposing here makes attn's V staging fully vectorized.
// ---------------------------------------------------------------------------
__global__ __launch_bounds__(256) void v_kernel(
    const float* __restrict__ latent, const float* __restrict__ Wv,
    ushort_t* __restrict__ v_t)
{
    __shared__ float wv[128 * 65];
    __shared__ float ls[64 * 65];
    const int t = threadIdx.x;
    const int m0 = blockIdx.x * 64;
    const int b = m0 >> 12, s0 = m0 & 4095;
    for (int i = t; i < 128 * 64; i += 256) wv[(i >> 6) * 65 + (i & 63)] = Wv[i];
    for (int i = t; i < 64 * 64; i += 256) ls[(i >> 6) * 65 + (i & 63)] = latent[(long)m0 * 64 + i];
    __syncthreads();
    const int sc = t & 7, dv0 = t >> 3;
    #pragma unroll
    for (int p = 0; p < 4; ++p) {
        const int dv = dv0 + 32 * p;
        float acc[8];
        #pragma unroll
        for (int j = 0; j < 8; ++j) acc[j] = 0.f;
        for (int l = 0; l < 64; ++l) {
            float f = wv[dv * 65 + l];
            #pragma unroll
            for (int j = 0; j < 8; ++j) acc[j] += f * ls[(sc * 8 + j) * 65 + l];
        }
        u16x8 o;
        #pragma unroll
        for (int j = 0; j < 8; ++j) o[j] = f2bf(acc[j]);
        *reinterpret_cast<u16x8*>(v_t + (long)(b * 128 + dv) * NS + s0 + sc * 8) = o;
    }
}

// ---------------------------------------------------------------------------
// attn: causal flash attention, 64 q-rows/block, KV tile 64, swapped QK^T.
// Balanced qt mapping + batch-aligned XCDs + 1-barrier prefetch pipeline.
// ---------------------------------------------------------------------------
__global__ __launch_bounds__(256) void attn_kernel(
    const ushort_t* __restrict__ q_bf, const ushort_t* __restrict__ k_bf,
    const ushort_t* __restrict__ v_t, float* __restrict__ out)
{
    __shared__ ushort_t Ks[2][64 * 64];
    __shared__ ushort_t Vts[2][128 * 64];
    __shared__ ushort_t Ps[4][16 * 64];
    const int tid = threadIdx.x;
    const int w = tid >> 6, lane = tid & 63, lg = lane >> 4, li = lane & 15;
    // balanced mapping: CU gets one heavy + one complementary light block
    const int l = blockIdx.x;
    int qt, b;
    if (l < 256) { qt = 63 - (l >> 3); b = l & 7; }
    else         { qt = (l - 256) >> 3; b = (l - 256) & 7; }
    const int Q0 = qt * 64;
    const float scale = 0.08838834764831845f;     // 128^-0.5
    const int srow = tid >> 3, scol = tid & 7;

    // Q fragments (B-operand): lane holds Q[Q0+16w+li][c*32+lg*8+j]
    const long qrow = (long)b * NS + Q0 + 16 * w + li;
    bf16x8 qf[2];
    qf[0] = *reinterpret_cast<const bf16x8*>(q_bf + qrow * NL + 0 + lg * 8);
    qf[1] = *reinterpret_cast<const bf16x8*>(q_bf + qrow * NL + 32 + lg * 8);

    float m_r = -3.0e38f, l_r = 0.f;
    f32x4 oacc[8];
    #pragma unroll
    for (int n = 0; n < 8; ++n) oacc[n] = f32x4{0.f, 0.f, 0.f, 0.f};

    u16x8 kreg[2], vreg[4];
    auto load_tile = [&](int kv0) {
        #pragma unroll
        for (int p = 0; p < 2; ++p)
            kreg[p] = *reinterpret_cast<const u16x8*>(
                k_bf + ((long)b * NS + kv0 + srow + 32 * p) * NL + scol * 8);
        #pragma unroll
        for (int p = 0; p < 4; ++p)
            vreg[p] = *reinterpret_cast<const u16x8*>(
                v_t + (long)(b * 128 + srow + 32 * p) * NS + kv0 + scol * 8);
    };
    auto write_tile = [&](int buf) {
        #pragma unroll
        for (int p = 0; p < 2; ++p)
            *reinterpret_cast<u16x8*>(reinterpret_cast<char*>(Ks[buf]) +
                swz(srow + 32 * p, scol * 16)) = kreg[p];
        #pragma unroll
        for (int p = 0; p < 4; ++p)
            *reinterpret_cast<u16x8*>(reinterpret_cast<char*>(Vts[buf]) +
                swz(srow + 32 * p, scol * 16)) = vreg[p];
    };

    load_tile(0);
    write_tile(0);
    __syncthreads();

    for (int t = 0; t <= qt; ++t) {
        const int cur = t & 1;
        if (t < qt) load_tile((t + 1) * 64);
        const char* Kb = reinterpret_cast<const char*>(Ks[cur]);
        const char* Vb = reinterpret_cast<const char*>(Vts[cur]);

        // S^T = K @ Q^T : lane holds col q=li, rows kv = 16f + 4lg + r
        f32x4 s[4];
        #pragma unroll
        for (int f = 0; f < 4; ++f) s[f] = f32x4{0.f, 0.f, 0.f, 0.f};
        #pragma unroll
        for (int c = 0; c < 2; ++c)
            #pragma unroll
            for (int f = 0; f < 4; ++f) {
                bf16x8 a = *reinterpret_cast<const bf16x8*>(Kb + swz(16 * f + li, c * 64 + lg * 16));
                s[f] = __builtin_amdgcn_mfma_f32_16x16x32_bf16(a, qf[c], s[f], 0, 0, 0);
            }

        // online softmax, lane owns q-row = li
        float p[16];
        float mx = -3.0e38f;
        const bool diag = (t == qt);
        #pragma unroll
        for (int f = 0; f < 4; ++f)
            #pragma unroll
            for (int r = 0; r < 4; ++r) {
                float v = s[f][r] * scale;
                if (diag && (16 * f + 4 * lg + r) > (16 * w + li)) v = -3.0e38f;
                p[f * 4 + r] = v;
                mx = fmaxf(mx, v);
            }
        mx = fmaxf(mx, __shfl_xor(mx, 16));
        mx = fmaxf(mx, __shfl_xor(mx, 32));
        float m_new = fmaxf(m_r, mx);
        float corr = __expf(m_r - m_new);
        float rs = 0.f;
        #pragma unroll
        for (int i = 0; i < 16; ++i) { p[i] = __expf(p[i] - m_new); rs += p[i]; }
        rs += __shfl_xor(rs, 16);
        rs += __shfl_xor(rs, 32);
        l_r = l_r * corr + rs;
        m_r = m_new;

        // write P[q=li][kv] bf16 pairs into per-wave LDS (swizzled)
        #pragma unroll
        for (int f = 0; f < 4; ++f)
            #pragma unroll
            for (int rp = 0; rp < 2; ++rp) {
                unsigned pk = (unsigned)f2bf(p[f * 4 + rp * 2]) |
                              ((unsigned)f2bf(p[f * 4 + rp * 2 + 1]) << 16);
                int kv = 16 * f + 4 * lg + rp * 2;
                *reinterpret_cast<unsigned*>(reinterpret_cast<char*>(Ps[w]) +
                    swz(li, kv * 2)) = pk;
            }

        // rescale O (O rows live at q = 4lg+r; state lives at lanes with li == q)
        float corrO[4];
        #pragma unroll
        for (int r = 0; r < 4; ++r)
            corrO[r] = __shfl(corr, (lane & 48) | (4 * lg + r));
        #pragma unroll
        for (int n = 0; n < 8; ++n)
            #pragma unroll
            for (int r = 0; r < 4; ++r) oacc[n][r] *= corrO[r];

        // O += P @ V
        #pragma unroll
        for (int c = 0; c < 2; ++c) {
            bf16x8 pa = *reinterpret_cast<const bf16x8*>(
                reinterpret_cast<const char*>(Ps[w]) + swz(li, c * 64 + lg * 16));
            #pragma unroll
            for (int n = 0; n < 8; ++n) {
                bf16x8 vb = *reinterpret_cast<const bf16x8*>(Vb + swz(16 * n + li, c * 64 + lg * 16));
                oacc[n] = __builtin_amdgcn_mfma_f32_16x16x32_bf16(pa, vb, oacc[n], 0, 0, 0);
            }
        }
        if (t < qt) write_tile(cur ^ 1);
        __syncthreads();
    }

    // epilogue: out[b, Q0+16w+4lg+r, 16n+li] = O / l
    float invl[4];
    #pragma unroll
    for (int r = 0; r < 4; ++r)
        invl[r] = __shfl(1.f / l_r, (lane & 48) | (4 * lg + r));
    #pragma unroll
    for (int n = 0; n < 8; ++n)
        #pragma unroll
        for (int r = 0; r < 4; ++r) {
            long row = (long)b * NS + Q0 + 16 * w + 4 * lg + r;
            out[row * NH + 16 * n + li] = oacc[n][r] * invl[r];
        }
}

// ---------------------------------------------------------------------------
extern "C" void kernel_launch(void* const* d_in, const int* in_sizes, int n_in,
                              void* d_out, int out_size, void* d_ws, size_t ws_size,
                              hipStream_t stream) {
    const float* x    = (const float*)d_in[0];
    const float* Wdkv = (const float*)d_in[1];
    const float* Wk   = (const float*)d_in[2];
    const float* Wv   = (const float*)d_in[3];
    const float* Wq   = (const float*)d_in[4];

    float* out = (float*)d_out;
    float* latent_out = out + (long)NM * NH;   // output 1 follows output 0

    // workspace layout
    ushort_t* WcatT = (ushort_t*)d_ws;                 // 128*2048 bf16 = 512 KB
    ushort_t* q_bf  = WcatT + 128 * NE;                // 4 MB
    ushort_t* k_bf  = q_bf + (long)NM * NL;            // 4 MB
    ushort_t* v_t   = k_bf + (long)NM * NL;            // 8 MB (transposed V)

    hipLaunchKernelGGL(prep_kernel, dim3(NE / 256), dim3(256), 0, stream, Wdkv, Wk, Wq, WcatT);
    hipLaunchKernelGGL(proj_kernel, dim3(NM / 64), dim3(256), 0, stream, x, WcatT, latent_out, k_bf, q_bf);
    hipLaunchKernelGGL(v_kernel, dim3(NM / 64), dim3(256), 0, stream, latent_out, Wv, v_t);
    hipLaunchKernelGGL(attn_kernel, dim3(512), dim3(256), 0, stream, q_bf, k_bf, v_t, out);
}

// Round 4
// 179.501 us; speedup vs baseline: 2.6125x; 1.5720x over previous
//
#include <hip/hip_runtime.h>
#include <hip/hip_bf16.h>

#define NB 8
#define NS 4096
#define NE 2048
#define NL 64
#define NH 128
#define NM (NB*NS)

typedef unsigned short ushort_t;
typedef __attribute__((ext_vector_type(4))) float f32x4;
typedef __attribute__((ext_vector_type(8))) __bf16 bf16x8;
typedef __attribute__((ext_vector_type(8))) unsigned short u16x8;

// 128^-0.5 * log2(e): folded into absorbed-q weights so attn can use exp2 directly
#define SCALE2 0.1275174537f

__device__ __forceinline__ float fast_exp2(float x) {
    return __builtin_amdgcn_exp2f(x);   // v_exp_f32: D = 2^S0
}

__device__ __forceinline__ unsigned short f2bf(float f) {
    union { float f; unsigned u; } v; v.f = f;
    unsigned u = v.u + 0x7fffu + ((v.u >> 16) & 1u);
    return (unsigned short)(u >> 16);
}

// XOR swizzle for 128-byte-stride LDS tiles (G4: fixes 16/32-way ds_read_b128 conflicts)
__device__ __forceinline__ int swz(int row, int colbyte) {
    return (row * 128 + colbyte) ^ ((row & 7) << 4);
}

// ---------------------------------------------------------------------------
// prep: WcatT[128][2048] bf16.  rows 0..63 = W_dkv, rows 64..127 = absorbed^T * SCALE2
// grid (8, 4): x = 256-col e-slab, y = 16-row l-quarter.
// ---------------------------------------------------------------------------
__global__ __launch_bounds__(256) void prep_kernel(
    const float* __restrict__ Wdkv, const float* __restrict__ Wk,
    const float* __restrict__ Wq, ushort_t* __restrict__ WcatT)
{
    __shared__ float wk[128 * 64];
    const int t = threadIdx.x;
    for (int i = t; i < 128 * 64; i += 256) wk[i] = Wk[i];
    __syncthreads();
    const int e = blockIdx.x * 256 + t;
    const int l0 = blockIdx.y * 16;
    float acc[16];
    #pragma unroll
    for (int l = 0; l < 16; ++l) acc[l] = 0.f;
    for (int h = 0; h < 128; ++h) {
        float q = Wq[h * NE + e];
        #pragma unroll
        for (int l = 0; l < 16; ++l) acc[l] += q * wk[h * 64 + l0 + l];
    }
    for (int l = 0; l < 16; ++l) WcatT[(64 + l0 + l) * NE + e] = f2bf(acc[l] * SCALE2);
    for (int l = 0; l < 16; ++l) WcatT[(l0 + l) * NE + e] = f2bf(Wdkv[(l0 + l) * NE + e]);
}

// ---------------------------------------------------------------------------
// proj: Y[M,128] = x[M,2048] @ WcatT^T.  BM=64,BN=128,BK=64, 4 waves (2x2).
// Depth-2 ping-pong register prefetch (two phases per loop body, static reg sets).
// Fused V epilogue: v_t[b][dv][s] = (latent @ Wv^T)^T via MFMA in the freed LDS.
// ---------------------------------------------------------------------------
__global__ __launch_bounds__(256) void proj_kernel(
    const float* __restrict__ x, const ushort_t* __restrict__ WcatT,
    const float* __restrict__ Wv,
    float* __restrict__ latent_out, ushort_t* __restrict__ k_bf,
    ushort_t* __restrict__ q_bf, ushort_t* __restrict__ v_t)
{
    __shared__ ushort_t As[2][64 * 64];
    __shared__ ushort_t Bs[2][128 * 64];
    const int tid = threadIdx.x;
    const int w = tid >> 6, lane = tid & 63, lg = lane >> 4, li = lane & 15;
    const int m0 = blockIdx.x * 64;
    const int wm = (w >> 1) * 32, wn = (w & 1) * 64;
    const int srow = tid >> 3, scol = tid & 7;

    f32x4 acc[2][4];
    #pragma unroll
    for (int i = 0; i < 2; ++i)
        #pragma unroll
        for (int j = 0; j < 4; ++j) acc[i][j] = f32x4{0.f, 0.f, 0.f, 0.f};

    f32x4 a0reg[2][2], a1reg[2][2];
    u16x8 b0reg[4], b1reg[4];

#define PLOAD(k0, AR, BR) do { \
    _Pragma("unroll") for (int p = 0; p < 2; ++p) { \
        const float* gp = x + (long)(m0 + srow + 32 * p) * NE + (k0) + scol * 8; \
        AR[p][0] = *reinterpret_cast<const f32x4*>(gp); \
        AR[p][1] = *reinterpret_cast<const f32x4*>(gp + 4); } \
    _Pragma("unroll") for (int p = 0; p < 4; ++p) \
        BR[p] = *reinterpret_cast<const u16x8*>(WcatT + (long)(srow + 32 * p) * NE + (k0) + scol * 8); \
} while (0)

#define PWRITE(AR, BR, buf) do { \
    _Pragma("unroll") for (int p = 0; p < 2; ++p) { \
        u16x8 h; \
        _Pragma("unroll") for (int j = 0; j < 4; ++j) { h[j] = f2bf(AR[p][0][j]); h[4 + j] = f2bf(AR[p][1][j]); } \
        *reinterpret_cast<u16x8*>(reinterpret_cast<char*>(As[buf]) + swz(srow + 32 * p, scol * 16)) = h; } \
    _Pragma("unroll") for (int p = 0; p < 4; ++p) \
        *reinterpret_cast<u16x8*>(reinterpret_cast<char*>(Bs[buf]) + swz(srow + 32 * p, scol * 16)) = BR[p]; \
} while (0)

    auto compute = [&](int buf) {
        #pragma unroll
        for (int c = 0; c < 2; ++c) {
            bf16x8 af[2], bfv[4];
            #pragma unroll
            for (int mf = 0; mf < 2; ++mf)
                af[mf] = *reinterpret_cast<const bf16x8*>(
                    reinterpret_cast<const char*>(As[buf]) + swz(wm + 16 * mf + li, c * 64 + lg * 16));
            #pragma unroll
            for (int nf = 0; nf < 4; ++nf)
                bfv[nf] = *reinterpret_cast<const bf16x8*>(
                    reinterpret_cast<const char*>(Bs[buf]) + swz(wn + 16 * nf + li, c * 64 + lg * 16));
            #pragma unroll
            for (int mf = 0; mf < 2; ++mf)
                #pragma unroll
                for (int nf = 0; nf < 4; ++nf)
                    acc[mf][nf] = __builtin_amdgcn_mfma_f32_16x16x32_bf16(
                        af[mf], bfv[nf], acc[mf][nf], 0, 0, 0);
        }
    };

    PLOAD(0, a0reg, b0reg);
    PLOAD(64, a1reg, b1reg);
    PWRITE(a0reg, b0reg, 0);
    __syncthreads();

    for (int ks = 0; ks < 32; ks += 2) {
        if (ks + 2 < 32) PLOAD((ks + 2) * 64, a0reg, b0reg);
        compute(0);
        PWRITE(a1reg, b1reg, 1);
        __syncthreads();
        if (ks + 3 < 32) PLOAD((ks + 3) * 64, a1reg, b1reg);
        compute(1);
        if (ks + 2 < 32) PWRITE(a0reg, b0reg, 0);
        __syncthreads();
    }

    // ---- epilogue: store latent(f32)+k(bf16)+q(bf16); stage latent bf16 -> As[0]
    const int b = m0 >> 12, s0 = m0 & 4095;
    #pragma unroll
    for (int mf = 0; mf < 2; ++mf) {
        #pragma unroll
        for (int nf = 0; nf < 4; ++nf) {
            int col = wn + 16 * nf + li;
            #pragma unroll
            for (int r = 0; r < 4; ++r) {
                int row = m0 + wm + 16 * mf + 4 * lg + r;
                float v = acc[mf][nf][r];
                if (wn == 0) {
                    latent_out[(long)row * NL + col] = v;
                    k_bf[(long)row * NL + col] = f2bf(v);
                    *reinterpret_cast<ushort_t*>(reinterpret_cast<char*>(As[0]) +
                        swz(wm + 16 * mf + 4 * lg + r, col * 2)) = f2bf(v);
                } else {
                    q_bf[(long)row * NL + (col - 64)] = f2bf(v);
                }
            }
        }
    }
    // stage Wv (f32 -> bf16) -> Bs[0]: [128 dv][64 l], swizzled
    {
        const int r = tid >> 1, hf = tid & 1;
        const float* wp = Wv + r * 64 + hf * 32;
        #pragma unroll
        for (int q = 0; q < 2; ++q) {
            f32x4 w0 = *reinterpret_cast<const f32x4*>(wp + q * 16);
            f32x4 w1 = *reinterpret_cast<const f32x4*>(wp + q * 16 + 4);
            f32x4 w2 = *reinterpret_cast<const f32x4*>(wp + q * 16 + 8);
            f32x4 w3 = *reinterpret_cast<const f32x4*>(wp + q * 16 + 12);
            u16x8 h0, h1;
            #pragma unroll
            for (int j = 0; j < 4; ++j) {
                h0[j] = f2bf(w0[j]); h0[4 + j] = f2bf(w1[j]);
                h1[j] = f2bf(w2[j]); h1[4 + j] = f2bf(w3[j]);
            }
            *reinterpret_cast<u16x8*>(reinterpret_cast<char*>(Bs[0]) + swz(r, hf * 64 + q * 32)) = h0;
            *reinterpret_cast<u16x8*>(reinterpret_cast<char*>(Bs[0]) + swz(r, hf * 64 + q * 32 + 16)) = h1;
        }
    }
    __syncthreads();
    // v GEMM: D[dv][s] = Wv[dv][l] * latent[s][l]; wave w owns dv rows 32w..32w+31
    f32x4 vacc[2][4];
    #pragma unroll
    for (int i = 0; i < 2; ++i)
        #pragma unroll
        for (int j = 0; j < 4; ++j) vacc[i][j] = f32x4{0.f, 0.f, 0.f, 0.f};
    #pragma unroll
    for (int c = 0; c < 2; ++c) {
        bf16x8 af[2], bfv[4];
        #pragma unroll
        for (int mf = 0; mf < 2; ++mf)
            af[mf] = *reinterpret_cast<const bf16x8*>(
                reinterpret_cast<const char*>(Bs[0]) + swz(32 * w + 16 * mf + li, c * 64 + lg * 16));
        #pragma unroll
        for (int nf = 0; nf < 4; ++nf)
            bfv[nf] = *reinterpret_cast<const bf16x8*>(
                reinterpret_cast<const char*>(As[0]) + swz(16 * nf + li, c * 64 + lg * 16));
        #pragma unroll
        for (int mf = 0; mf < 2; ++mf)
            #pragma unroll
            for (int nf = 0; nf < 4; ++nf)
                vacc[mf][nf] = __builtin_amdgcn_mfma_f32_16x16x32_bf16(
                    af[mf], bfv[nf], vacc[mf][nf], 0, 0, 0);
    }
    #pragma unroll
    for (int mf = 0; mf < 2; ++mf)
        #pragma unroll
        for (int nf = 0; nf < 4; ++nf)
            #pragma unroll
            for (int r = 0; r < 4; ++r)
                v_t[(long)(b * 128 + 32 * w + 16 * mf + 4 * lg + r) * NS + s0 + 16 * nf + li] =
                    f2bf(vacc[mf][nf][r]);
}

// ---------------------------------------------------------------------------
// attn: causal flash attention, 64 q-rows/block, KV tile 64, swapped QK^T.
// Balanced qt mapping + batch-aligned XCDs + depth-2 ping-pong prefetch.
// ---------------------------------------------------------------------------
__global__ __launch_bounds__(256) void attn_kernel(
    const ushort_t* __restrict__ q_bf, const ushort_t* __restrict__ k_bf,
    const ushort_t* __restrict__ v_t, float* __restrict__ out)
{
    __shared__ ushort_t Ks[2][64 * 64];
    __shared__ ushort_t Vts[2][128 * 64];
    __shared__ ushort_t Ps[4][16 * 64];
    const int tid = threadIdx.x;
    const int w = tid >> 6, lane = tid & 63, lg = lane >> 4, li = lane & 15;
    const int l = blockIdx.x;
    int qt, b;
    if (l < 256) { qt = 63 - (l >> 3); b = l & 7; }
    else         { qt = (l - 256) >> 3; b = (l - 256) & 7; }
    const int Q0 = qt * 64;
    const int srow = tid >> 3, scol = tid & 7;

    // Q fragments (B-operand), pre-scaled by SCALE2 at prep time
    const long qrow = (long)b * NS + Q0 + 16 * w + li;
    bf16x8 qf[2];
    qf[0] = *reinterpret_cast<const bf16x8*>(q_bf + qrow * NL + 0 + lg * 8);
    qf[1] = *reinterpret_cast<const bf16x8*>(q_bf + qrow * NL + 32 + lg * 8);

    float m_r = -3.0e38f, l_r = 0.f;
    f32x4 oacc[8];
    #pragma unroll
    for (int n = 0; n < 8; ++n) oacc[n] = f32x4{0.f, 0.f, 0.f, 0.f};

    u16x8 k0reg[2], v0reg[4], k1reg[2], v1reg[4];

#define ALOAD(kv0, KR, VR) do { \
    _Pragma("unroll") for (int p = 0; p < 2; ++p) \
        KR[p] = *reinterpret_cast<const u16x8*>(k_bf + ((long)b * NS + (kv0) + srow + 32 * p) * NL + scol * 8); \
    _Pragma("unroll") for (int p = 0; p < 4; ++p) \
        VR[p] = *reinterpret_cast<const u16x8*>(v_t + (long)(b * 128 + srow + 32 * p) * NS + (kv0) + scol * 8); \
} while (0)

#define AWRITE(KR, VR, buf) do { \
    _Pragma("unroll") for (int p = 0; p < 2; ++p) \
        *reinterpret_cast<u16x8*>(reinterpret_cast<char*>(Ks[buf]) + swz(srow + 32 * p, scol * 16)) = KR[p]; \
    _Pragma("unroll") for (int p = 0; p < 4; ++p) \
        *reinterpret_cast<u16x8*>(reinterpret_cast<char*>(Vts[buf]) + swz(srow + 32 * p, scol * 16)) = VR[p]; \
} while (0)

    auto compute = [&](int buf, bool diag) {
        const char* Kb = reinterpret_cast<const char*>(Ks[buf]);
        const char* Vb = reinterpret_cast<const char*>(Vts[buf]);
        // S^T = K @ Q^T : lane holds col q=li, rows kv = 16f + 4lg + r
        f32x4 s[4];
        #pragma unroll
        for (int f = 0; f < 4; ++f) s[f] = f32x4{0.f, 0.f, 0.f, 0.f};
        #pragma unroll
        for (int c = 0; c < 2; ++c)
            #pragma unroll
            for (int f = 0; f < 4; ++f) {
                bf16x8 a = *reinterpret_cast<const bf16x8*>(Kb + swz(16 * f + li, c * 64 + lg * 16));
                s[f] = __builtin_amdgcn_mfma_f32_16x16x32_bf16(a, qf[c], s[f], 0, 0, 0);
            }
        // online softmax (log2 domain; scale folded into q), lane owns q-row = li
        float p[16];
        float mx = -3.0e38f;
        #pragma unroll
        for (int f = 0; f < 4; ++f)
            #pragma unroll
            for (int r = 0; r < 4; ++r) {
                float v = s[f][r];
                if (diag && (16 * f + 4 * lg + r) > (16 * w + li)) v = -3.0e38f;
                p[f * 4 + r] = v;
                mx = fmaxf(mx, v);
            }
        mx = fmaxf(mx, __shfl_xor(mx, 16));
        mx = fmaxf(mx, __shfl_xor(mx, 32));
        float m_new = fmaxf(m_r, mx);
        float corr = fast_exp2(m_r - m_new);
        float rs = 0.f;
        #pragma unroll
        for (int i = 0; i < 16; ++i) { p[i] = fast_exp2(p[i] - m_new); rs += p[i]; }
        rs += __shfl_xor(rs, 16);
        rs += __shfl_xor(rs, 32);
        l_r = l_r * corr + rs;
        m_r = m_new;
        // write P[q=li][kv] bf16 pairs into per-wave LDS (swizzled)
        #pragma unroll
        for (int f = 0; f < 4; ++f)
            #pragma unroll
            for (int rp = 0; rp < 2; ++rp) {
                unsigned pk = (unsigned)f2bf(p[f * 4 + rp * 2]) |
                              ((unsigned)f2bf(p[f * 4 + rp * 2 + 1]) << 16);
                int kv = 16 * f + 4 * lg + rp * 2;
                *reinterpret_cast<unsigned*>(reinterpret_cast<char*>(Ps[w]) + swz(li, kv * 2)) = pk;
            }
        // rescale O
        float corrO[4];
        #pragma unroll
        for (int r = 0; r < 4; ++r)
            corrO[r] = __shfl(corr, (lane & 48) | (4 * lg + r));
        #pragma unroll
        for (int n = 0; n < 8; ++n)
            #pragma unroll
            for (int r = 0; r < 4; ++r) oacc[n][r] *= corrO[r];
        // O += P @ V
        #pragma unroll
        for (int c = 0; c < 2; ++c) {
            bf16x8 pa = *reinterpret_cast<const bf16x8*>(
                reinterpret_cast<const char*>(Ps[w]) + swz(li, c * 64 + lg * 16));
            #pragma unroll
            for (int n = 0; n < 8; ++n) {
                bf16x8 vb = *reinterpret_cast<const bf16x8*>(Vb + swz(16 * n + li, c * 64 + lg * 16));
                oacc[n] = __builtin_amdgcn_mfma_f32_16x16x32_bf16(pa, vb, oacc[n], 0, 0, 0);
            }
        }
    };

    ALOAD(0, k0reg, v0reg);
    if (qt >= 1) ALOAD(64, k1reg, v1reg);
    AWRITE(k0reg, v0reg, 0);
    __syncthreads();

    for (int t = 0; t <= qt; t += 2) {
        if (t + 2 <= qt) ALOAD((t + 2) * 64, k0reg, v0reg);
        compute(0, t == qt);
        if (t + 1 <= qt) AWRITE(k1reg, v1reg, 1);
        __syncthreads();
        if (t + 1 > qt) break;
        if (t + 3 <= qt) ALOAD((t + 3) * 64, k1reg, v1reg);
        compute(1, t + 1 == qt);
        if (t + 2 <= qt) AWRITE(k0reg, v0reg, 0);
        __syncthreads();
    }

    // epilogue: out[b, Q0+16w+4lg+r, 16n+li] = O / l
    float invl[4];
    #pragma unroll
    for (int r = 0; r < 4; ++r)
        invl[r] = __shfl(1.f / l_r, (lane & 48) | (4 * lg + r));
    #pragma unroll
    for (int n = 0; n < 8; ++n)
        #pragma unroll
        for (int r = 0; r < 4; ++r) {
            long row = (long)b * NS + Q0 + 16 * w + 4 * lg + r;
            out[row * NH + 16 * n + li] = oacc[n][r] * invl[r];
        }
}

// ---------------------------------------------------------------------------
extern "C" void kernel_launch(void* const* d_in, const int* in_sizes, int n_in,
                              void* d_out, int out_size, void* d_ws, size_t ws_size,
                              hipStream_t stream) {
    const float* x    = (const float*)d_in[0];
    const float* Wdkv = (const float*)d_in[1];
    const float* Wk   = (const float*)d_in[2];
    const float* Wv   = (const float*)d_in[3];
    const float* Wq   = (const float*)d_in[4];

    float* out = (float*)d_out;
    float* latent_out = out + (long)NM * NH;   // output 1 follows output 0

    // workspace layout
    ushort_t* WcatT = (ushort_t*)d_ws;                 // 512 KB
    ushort_t* q_bf  = WcatT + 128 * NE;                // 4 MB
    ushort_t* k_bf  = q_bf + (long)NM * NL;            // 4 MB
    ushort_t* v_t   = k_bf + (long)NM * NL;            // 8 MB (transposed V)

    hipLaunchKernelGGL(prep_kernel, dim3(NE / 256, 4), dim3(256), 0, stream, Wdkv, Wk, Wq, WcatT);
    hipLaunchKernelGGL(proj_kernel, dim3(NM / 64), dim3(256), 0, stream,
                       x, WcatT, Wv, latent_out, k_bf, q_bf, v_t);
    hipLaunchKernelGGL(attn_kernel, dim3(512), dim3(256), 0, stream, q_bf, k_bf, v_t, out);
}

// Round 5
// 173.458 us; speedup vs baseline: 2.7035x; 1.0348x over previous
//
#include <hip/hip_runtime.h>
#include <hip/hip_bf16.h>

#define NB 8
#define NS 4096
#define NE 2048
#define NL 64
#define NH 128
#define NM (NB*NS)

typedef unsigned short ushort_t;
typedef __attribute__((ext_vector_type(4))) float f32x4;
typedef __attribute__((ext_vector_type(8))) __bf16 bf16x8;
typedef __attribute__((ext_vector_type(8))) unsigned short u16x8;
typedef __attribute__((ext_vector_type(4))) unsigned short u16x4;

// 128^-0.5 * log2(e): folded into absorbed-q weights so attn uses exp2 directly
#define SCALE2 0.1275174537f

__device__ __forceinline__ float fast_exp2(float x) {
    return __builtin_amdgcn_exp2f(x);   // v_exp_f32: D = 2^S0
}

__device__ __forceinline__ unsigned short f2bf(float f) {
    union { float f; unsigned u; } v; v.f = f;
    unsigned u = v.u + 0x7fffu + ((v.u >> 16) & 1u);
    return (unsigned short)(u >> 16);
}

// XOR swizzle for 128-byte-stride LDS tiles (G4: fixes 16/32-way ds_read_b128 conflicts)
__device__ __forceinline__ int swz(int row, int colbyte) {
    return (row * 128 + colbyte) ^ ((row & 7) << 4);
}

// Raw barrier: LDS visibility only — does NOT drain vmcnt, so prefetch loads
// stay in flight across the barrier (T4). sched_barrier pins LDS reads below.
__device__ __forceinline__ void wg_barrier() {
    asm volatile("s_waitcnt lgkmcnt(0)" ::: "memory");
    __builtin_amdgcn_s_barrier();
    __builtin_amdgcn_sched_barrier(0);
}

// ---------------------------------------------------------------------------
// prep: WcatT[128][2048] bf16.  rows 0..63 = W_dkv, rows 64..127 = absorbed^T * SCALE2
// ---------------------------------------------------------------------------
__global__ __launch_bounds__(256) void prep_kernel(
    const float* __restrict__ Wdkv, const float* __restrict__ Wk,
    const float* __restrict__ Wq, ushort_t* __restrict__ WcatT)
{
    __shared__ float wk[128 * 64];
    const int t = threadIdx.x;
    for (int i = t; i < 128 * 64; i += 256) wk[i] = Wk[i];
    __syncthreads();
    const int e = blockIdx.x * 256 + t;
    const int l0 = blockIdx.y * 16;
    float acc[16];
    #pragma unroll
    for (int l = 0; l < 16; ++l) acc[l] = 0.f;
    for (int h = 0; h < 128; ++h) {
        float q = Wq[h * NE + e];
        #pragma unroll
        for (int l = 0; l < 16; ++l) acc[l] += q * wk[h * 64 + l0 + l];
    }
    for (int l = 0; l < 16; ++l) WcatT[(64 + l0 + l) * NE + e] = f2bf(acc[l] * SCALE2);
    for (int l = 0; l < 16; ++l) WcatT[(l0 + l) * NE + e] = f2bf(Wdkv[(l0 + l) * NE + e]);
}

// ---------------------------------------------------------------------------
// proj: Y[M,128] = x[M,2048] @ WcatT^T.  BM=64,BN=128,BK=64, 4 waves (2x2).
// Depth-2 ping-pong register prefetch + raw barriers (loads stay in flight).
// Fused V epilogue: v_t[b][dv][s] = (latent @ Wv^T)^T.
// ---------------------------------------------------------------------------
__global__ __launch_bounds__(256) void proj_kernel(
    const float* __restrict__ x, const ushort_t* __restrict__ WcatT,
    const float* __restrict__ Wv,
    float* __restrict__ latent_out, ushort_t* __restrict__ k_bf,
    ushort_t* __restrict__ q_bf, ushort_t* __restrict__ v_t)
{
    __shared__ ushort_t As[2][64 * 64];
    __shared__ ushort_t Bs[2][128 * 64];
    const int tid = threadIdx.x;
    const int w = tid >> 6, lane = tid & 63, lg = lane >> 4, li = lane & 15;
    const int m0 = blockIdx.x * 64;
    const int wm = (w >> 1) * 32, wn = (w & 1) * 64;
    const int srow = tid >> 3, scol = tid & 7;

    f32x4 acc[2][4];
    #pragma unroll
    for (int i = 0; i < 2; ++i)
        #pragma unroll
        for (int j = 0; j < 4; ++j) acc[i][j] = f32x4{0.f, 0.f, 0.f, 0.f};

    f32x4 a0reg[2][2], a1reg[2][2];
    u16x8 b0reg[4], b1reg[4];

#define PLOAD(k0, AR, BR) do { \
    _Pragma("unroll") for (int p = 0; p < 2; ++p) { \
        const float* gp = x + (long)(m0 + srow + 32 * p) * NE + (k0) + scol * 8; \
        AR[p][0] = *reinterpret_cast<const f32x4*>(gp); \
        AR[p][1] = *reinterpret_cast<const f32x4*>(gp + 4); } \
    _Pragma("unroll") for (int p = 0; p < 4; ++p) \
        BR[p] = *reinterpret_cast<const u16x8*>(WcatT + (long)(srow + 32 * p) * NE + (k0) + scol * 8); \
} while (0)

#define PWRITE(AR, BR, buf) do { \
    _Pragma("unroll") for (int p = 0; p < 2; ++p) { \
        u16x8 h; \
        _Pragma("unroll") for (int j = 0; j < 4; ++j) { h[j] = f2bf(AR[p][0][j]); h[4 + j] = f2bf(AR[p][1][j]); } \
        *reinterpret_cast<u16x8*>(reinterpret_cast<char*>(As[buf]) + swz(srow + 32 * p, scol * 16)) = h; } \
    _Pragma("unroll") for (int p = 0; p < 4; ++p) \
        *reinterpret_cast<u16x8*>(reinterpret_cast<char*>(Bs[buf]) + swz(srow + 32 * p, scol * 16)) = BR[p]; \
} while (0)

    auto compute = [&](int buf) {
        #pragma unroll
        for (int c = 0; c < 2; ++c) {
            bf16x8 af[2], bfv[4];
            #pragma unroll
            for (int mf = 0; mf < 2; ++mf)
                af[mf] = *reinterpret_cast<const bf16x8*>(
                    reinterpret_cast<const char*>(As[buf]) + swz(wm + 16 * mf + li, c * 64 + lg * 16));
            #pragma unroll
            for (int nf = 0; nf < 4; ++nf)
                bfv[nf] = *reinterpret_cast<const bf16x8*>(
                    reinterpret_cast<const char*>(Bs[buf]) + swz(wn + 16 * nf + li, c * 64 + lg * 16));
            #pragma unroll
            for (int mf = 0; mf < 2; ++mf)
                #pragma unroll
                for (int nf = 0; nf < 4; ++nf)
                    acc[mf][nf] = __builtin_amdgcn_mfma_f32_16x16x32_bf16(
                        af[mf], bfv[nf], acc[mf][nf], 0, 0, 0);
        }
    };

    PLOAD(0, a0reg, b0reg);
    PLOAD(64, a1reg, b1reg);
    PWRITE(a0reg, b0reg, 0);
    wg_barrier();

    for (int ks = 0; ks < 32; ks += 2) {
        if (ks + 2 < 32) PLOAD((ks + 2) * 64, a0reg, b0reg);
        compute(0);
        PWRITE(a1reg, b1reg, 1);
        wg_barrier();
        if (ks + 3 < 32) PLOAD((ks + 3) * 64, a1reg, b1reg);
        compute(1);
        if (ks + 2 < 32) PWRITE(a0reg, b0reg, 0);
        wg_barrier();
    }

    // ---- epilogue: store latent(f32)+k(bf16)+q(bf16); stage latent bf16 -> As[0]
    const int b = m0 >> 12, s0 = m0 & 4095;
    #pragma unroll
    for (int mf = 0; mf < 2; ++mf) {
        #pragma unroll
        for (int nf = 0; nf < 4; ++nf) {
            int col = wn + 16 * nf + li;
            #pragma unroll
            for (int r = 0; r < 4; ++r) {
                int row = m0 + wm + 16 * mf + 4 * lg + r;
                float v = acc[mf][nf][r];
                if (wn == 0) {
                    latent_out[(long)row * NL + col] = v;
                    k_bf[(long)row * NL + col] = f2bf(v);
                    *reinterpret_cast<ushort_t*>(reinterpret_cast<char*>(As[0]) +
                        swz(wm + 16 * mf + 4 * lg + r, col * 2)) = f2bf(v);
                } else {
                    q_bf[(long)row * NL + (col - 64)] = f2bf(v);
                }
            }
        }
    }
    // stage Wv (f32 -> bf16) -> Bs[0]: [128 dv][64 l], swizzled
    {
        const int r = tid >> 1, hf = tid & 1;
        const float* wp = Wv + r * 64 + hf * 32;
        #pragma unroll
        for (int q = 0; q < 2; ++q) {
            f32x4 w0 = *reinterpret_cast<const f32x4*>(wp + q * 16);
            f32x4 w1 = *reinterpret_cast<const f32x4*>(wp + q * 16 + 4);
            f32x4 w2 = *reinterpret_cast<const f32x4*>(wp + q * 16 + 8);
            f32x4 w3 = *reinterpret_cast<const f32x4*>(wp + q * 16 + 12);
            u16x8 h0, h1;
            #pragma unroll
            for (int j = 0; j < 4; ++j) {
                h0[j] = f2bf(w0[j]); h0[4 + j] = f2bf(w1[j]);
                h1[j] = f2bf(w2[j]); h1[4 + j] = f2bf(w3[j]);
            }
            *reinterpret_cast<u16x8*>(reinterpret_cast<char*>(Bs[0]) + swz(r, hf * 64 + q * 32)) = h0;
            *reinterpret_cast<u16x8*>(reinterpret_cast<char*>(Bs[0]) + swz(r, hf * 64 + q * 32 + 16)) = h1;
        }
    }
    wg_barrier();
    // v GEMM: D[dv][s] = Wv[dv][l] * latent[s][l]; wave w owns dv rows 32w..32w+31
    f32x4 vacc[2][4];
    #pragma unroll
    for (int i = 0; i < 2; ++i)
        #pragma unroll
        for (int j = 0; j < 4; ++j) vacc[i][j] = f32x4{0.f, 0.f, 0.f, 0.f};
    #pragma unroll
    for (int c = 0; c < 2; ++c) {
        bf16x8 af[2], bfv[4];
        #pragma unroll
        for (int mf = 0; mf < 2; ++mf)
            af[mf] = *reinterpret_cast<const bf16x8*>(
                reinterpret_cast<const char*>(Bs[0]) + swz(32 * w + 16 * mf + li, c * 64 + lg * 16));
        #pragma unroll
        for (int nf = 0; nf < 4; ++nf)
            bfv[nf] = *reinterpret_cast<const bf16x8*>(
                reinterpret_cast<const char*>(As[0]) + swz(16 * nf + li, c * 64 + lg * 16));
        #pragma unroll
        for (int mf = 0; mf < 2; ++mf)
            #pragma unroll
            for (int nf = 0; nf < 4; ++nf)
                vacc[mf][nf] = __builtin_amdgcn_mfma_f32_16x16x32_bf16(
                    af[mf], bfv[nf], vacc[mf][nf], 0, 0, 0);
    }
    #pragma unroll
    for (int mf = 0; mf < 2; ++mf)
        #pragma unroll
        for (int nf = 0; nf < 4; ++nf)
            #pragma unroll
            for (int r = 0; r < 4; ++r)
                v_t[(long)(b * 128 + 32 * w + 16 * mf + 4 * lg + r) * NS + s0 + 16 * nf + li] =
                    f2bf(vacc[mf][nf][r]);
}

// ---------------------------------------------------------------------------
// attn: causal flash attention, 64 q-rows/block (4 waves x 16q), KV tile 64.
// Swapped QK^T; P stays IN REGISTERS: V is stored kv-PERMUTED in LDS so that
// the QK^T D-layout matches the PV A-operand layout exactly.
//   pi(kv): kv' bits = [kv4][kv3][kv2][kv5][kv1][kv0]  (bijection, exact)
// Raw barriers (no vmcnt drain) keep depth-2 prefetch loads in flight.
// ---------------------------------------------------------------------------
__global__ __launch_bounds__(256) void attn_kernel(
    const ushort_t* __restrict__ q_bf, const ushort_t* __restrict__ k_bf,
    const ushort_t* __restrict__ v_t, float* __restrict__ out)
{
    __shared__ ushort_t Ks[2][64 * 64];
    __shared__ ushort_t Vts[2][128 * 64];   // [dv][kv'] permuted columns
    const int tid = threadIdx.x;
    const int w = tid >> 6, lane = tid & 63, lg = lane >> 4, li = lane & 15;
    const int l = blockIdx.x;
    int qt, b;
    if (l < 256) { qt = 63 - (l >> 3); b = l & 7; }
    else         { qt = (l - 256) >> 3; b = (l - 256) & 7; }
    const int Q0 = qt * 64;
    const int srow = tid >> 3, scol = tid & 7;
    // V-stage permuted column base (bytes): kv natural = scol*8+e ->
    // kv' = 32*scol.b1 + 16*scol.b0 + 8*e.b2 + 4*scol.b2 + (e&3)
    const int vc0 = 64 * ((scol >> 1) & 1) + 32 * (scol & 1) + 8 * (scol >> 2);

    // Q fragments (B-operand), pre-scaled by SCALE2*ln2-fold at prep time
    const long qrow = (long)b * NS + Q0 + 16 * w + li;
    bf16x8 qf[2];
    qf[0] = *reinterpret_cast<const bf16x8*>(q_bf + qrow * NL + 0 + lg * 8);
    qf[1] = *reinterpret_cast<const bf16x8*>(q_bf + qrow * NL + 32 + lg * 8);

    float m_r = -3.0e38f, l_r = 0.f;
    f32x4 oacc[8];
    #pragma unroll
    for (int n = 0; n < 8; ++n) oacc[n] = f32x4{0.f, 0.f, 0.f, 0.f};

    u16x8 k0reg[2], v0reg[4], k1reg[2], v1reg[4];

#define ALOAD(kv0, KR, VR) do { \
    _Pragma("unroll") for (int p = 0; p < 2; ++p) \
        KR[p] = *reinterpret_cast<const u16x8*>(k_bf + ((long)b * NS + (kv0) + srow + 32 * p) * NL + scol * 8); \
    _Pragma("unroll") for (int p = 0; p < 4; ++p) \
        VR[p] = *reinterpret_cast<const u16x8*>(v_t + (long)(b * 128 + srow + 32 * p) * NS + (kv0) + scol * 8); \
} while (0)

#define AWRITE(KR, VR, buf) do { \
    _Pragma("unroll") for (int p = 0; p < 2; ++p) \
        *reinterpret_cast<u16x8*>(reinterpret_cast<char*>(Ks[buf]) + swz(srow + 32 * p, scol * 16)) = KR[p]; \
    _Pragma("unroll") for (int p = 0; p < 4; ++p) { \
        u16x4 lo = {VR[p][0], VR[p][1], VR[p][2], VR[p][3]}; \
        u16x4 hi = {VR[p][4], VR[p][5], VR[p][6], VR[p][7]}; \
        *reinterpret_cast<u16x4*>(reinterpret_cast<char*>(Vts[buf]) + swz(srow + 32 * p, vc0)) = lo; \
        *reinterpret_cast<u16x4*>(reinterpret_cast<char*>(Vts[buf]) + swz(srow + 32 * p, vc0 + 16)) = hi; \
    } \
} while (0)

    auto compute = [&](int buf, bool diag) {
        const char* Kb = reinterpret_cast<const char*>(Ks[buf]);
        const char* Vb = reinterpret_cast<const char*>(Vts[buf]);
        // S^T = K @ Q^T : lane holds col q=li, rows kv = 16f + 4lg + r
        f32x4 s[4];
        #pragma unroll
        for (int f = 0; f < 4; ++f) s[f] = f32x4{0.f, 0.f, 0.f, 0.f};
        __builtin_amdgcn_s_setprio(1);
        #pragma unroll
        for (int c = 0; c < 2; ++c)
            #pragma unroll
            for (int f = 0; f < 4; ++f) {
                bf16x8 a = *reinterpret_cast<const bf16x8*>(Kb + swz(16 * f + li, c * 64 + lg * 16));
                s[f] = __builtin_amdgcn_mfma_f32_16x16x32_bf16(a, qf[c], s[f], 0, 0, 0);
            }
        __builtin_amdgcn_s_setprio(0);
        // online softmax (log2 domain), lane owns q-row = li, p[i] kv=16(i>>2)+4lg+(i&3)
        float p[16];
        float mx = -3.0e38f;
        #pragma unroll
        for (int f = 0; f < 4; ++f)
            #pragma unroll
            for (int r = 0; r < 4; ++r) {
                float v = s[f][r];
                if (diag && (16 * f + 4 * lg + r) > (16 * w + li)) v = -3.0e38f;
                p[f * 4 + r] = v;
                mx = fmaxf(mx, v);
            }
        mx = fmaxf(mx, __shfl_xor(mx, 16));
        mx = fmaxf(mx, __shfl_xor(mx, 32));
        // defer-max (T13): skip rescale while max grows < 8 (P bounded by 2^8)
        if (!__all(mx <= m_r + 8.f)) {
            float m_new = fmaxf(m_r, mx);
            float corr = fast_exp2(m_r - m_new);
            m_r = m_new;
            l_r *= corr;
            float corrO[4];
            #pragma unroll
            for (int r = 0; r < 4; ++r)
                corrO[r] = __shfl(corr, (lane & 48) | (4 * lg + r));
            #pragma unroll
            for (int n = 0; n < 8; ++n)
                #pragma unroll
                for (int r = 0; r < 4; ++r) oacc[n][r] *= corrO[r];
        }
        float rs = 0.f;
        #pragma unroll
        for (int i = 0; i < 16; ++i) { p[i] = fast_exp2(p[i] - m_r); rs += p[i]; }
        rs += __shfl_xor(rs, 16);
        rs += __shfl_xor(rs, 32);
        l_r += rs;
        // pack P to bf16 pairs in-register: pw[2f+h] = (p[4f+2h], p[4f+2h+1])
        unsigned pw[8];
        #pragma unroll
        for (int f = 0; f < 4; ++f)
            #pragma unroll
            for (int h = 0; h < 2; ++h)
                asm("v_cvt_pk_bf16_f32 %0, %1, %2"
                    : "=v"(pw[2 * f + h]) : "v"(p[4 * f + 2 * h]), "v"(p[4 * f + 2 * h + 1]));
        // A-fragments directly from pw (kv-permutation absorbed into V layout):
        // pa[c].word[m] = pw[4*(m>>1) + 2c + (m&1)]
        union { unsigned u[4]; bf16x8 v; } pa0, pa1;
        pa0.u[0] = pw[0]; pa0.u[1] = pw[1]; pa0.u[2] = pw[4]; pa0.u[3] = pw[5];
        pa1.u[0] = pw[2]; pa1.u[1] = pw[3]; pa1.u[2] = pw[6]; pa1.u[3] = pw[7];
        // O += P @ V
        __builtin_amdgcn_s_setprio(1);
        #pragma unroll
        for (int c = 0; c < 2; ++c) {
            bf16x8 pa = c ? pa1.v : pa0.v;
            #pragma unroll
            for (int n = 0; n < 8; ++n) {
                bf16x8 vb = *reinterpret_cast<const bf16x8*>(Vb + swz(16 * n + li, c * 64 + lg * 16));
                oacc[n] = __builtin_amdgcn_mfma_f32_16x16x32_bf16(pa, vb, oacc[n], 0, 0, 0);
            }
        }
        __builtin_amdgcn_s_setprio(0);
    };

    ALOAD(0, k0reg, v0reg);
    if (qt >= 1) ALOAD(64, k1reg, v1reg);
    AWRITE(k0reg, v0reg, 0);
    wg_barrier();

    for (int t = 0; t <= qt; t += 2) {
        if (t + 2 <= qt) ALOAD((t + 2) * 64, k0reg, v0reg);
        compute(0, t == qt);
        if (t + 1 <= qt) AWRITE(k1reg, v1reg, 1);
        wg_barrier();
        if (t + 1 > qt) break;
        if (t + 3 <= qt) ALOAD((t + 3) * 64, k1reg, v1reg);
        compute(1, t + 1 == qt);
        if (t + 2 <= qt) AWRITE(k0reg, v0reg, 0);
        wg_barrier();
    }

    // epilogue: out[b, Q0+16w+4lg+r, 16n+li] = O / l
    float invl[4];
    #pragma unroll
    for (int r = 0; r < 4; ++r)
        invl[r] = __shfl(1.f / l_r, (lane & 48) | (4 * lg + r));
    #pragma unroll
    for (int n = 0; n < 8; ++n)
        #pragma unroll
        for (int r = 0; r < 4; ++r) {
            long row = (long)b * NS + Q0 + 16 * w + 4 * lg + r;
            out[row * NH + 16 * n + li] = oacc[n][r] * invl[r];
        }
}

// ---------------------------------------------------------------------------
extern "C" void kernel_launch(void* const* d_in, const int* in_sizes, int n_in,
                              void* d_out, int out_size, void* d_ws, size_t ws_size,
                              hipStream_t stream) {
    const float* x    = (const float*)d_in[0];
    const float* Wdkv = (const float*)d_in[1];
    const float* Wk   = (const float*)d_in[2];
    const float* Wv   = (const float*)d_in[3];
    const float* Wq   = (const float*)d_in[4];

    float* out = (float*)d_out;
    float* latent_out = out + (long)NM * NH;   // output 1 follows output 0

    // workspace layout
    ushort_t* WcatT = (ushort_t*)d_ws;                 // 512 KB
    ushort_t* q_bf  = WcatT + 128 * NE;                // 4 MB
    ushort_t* k_bf  = q_bf + (long)NM * NL;            // 4 MB
    ushort_t* v_t   = k_bf + (long)NM * NL;            // 8 MB (transposed V)

    hipLaunchKernelGGL(prep_kernel, dim3(NE / 256, 4), dim3(256), 0, stream, Wdkv, Wk, Wq, WcatT);
    hipLaunchKernelGGL(proj_kernel, dim3(NM / 64), dim3(256), 0, stream,
                       x, WcatT, Wv, latent_out, k_bf, q_bf, v_t);
    hipLaunchKernelGGL(attn_kernel, dim3(512), dim3(256), 0, stream, q_bf, k_bf, v_t, out);
}

// Round 6
// 161.099 us; speedup vs baseline: 2.9110x; 1.0767x over previous
//
#include <hip/hip_runtime.h>
#include <hip/hip_bf16.h>

#define NB 8
#define NS 4096
#define NE 2048
#define NL 64
#define NH 128
#define NM (NB*NS)
#define NQT (NS/64)   // 64 q-tiles per batch

typedef unsigned short ushort_t;
typedef __attribute__((ext_vector_type(4))) float f32x4;
typedef __attribute__((ext_vector_type(8))) __bf16 bf16x8;
typedef __attribute__((ext_vector_type(8))) unsigned short u16x8;
typedef __attribute__((ext_vector_type(4))) unsigned short u16x4;

// 128^-0.5 * log2(e): folded into absorbed-q weights so attn uses exp2 directly
#define SCALE2 0.1275174537f

__device__ __forceinline__ float fast_exp2(float x) {
    return __builtin_amdgcn_exp2f(x);   // v_exp_f32: D = 2^S0
}

__device__ __forceinline__ unsigned short f2bf(float f) {
    union { float f; unsigned u; } v; v.f = f;
    unsigned u = v.u + 0x7fffu + ((v.u >> 16) & 1u);
    return (unsigned short)(u >> 16);
}

// XOR swizzle for 128-byte-stride LDS tiles (G4: fixes 16/32-way ds_read_b128 conflicts)
__device__ __forceinline__ int swz(int row, int colbyte) {
    return (row * 128 + colbyte) ^ ((row & 7) << 4);
}

// Raw barrier: LDS visibility only — does NOT drain vmcnt (T4).
__device__ __forceinline__ void wg_barrier() {
    asm volatile("s_waitcnt lgkmcnt(0)" ::: "memory");
    __builtin_amdgcn_s_barrier();
    __builtin_amdgcn_sched_barrier(0);
}

// ---------------------------------------------------------------------------
// prep: WcatT[128][2048] bf16.  rows 0..63 = W_dkv, rows 64..127 = absorbed^T * SCALE2
// ---------------------------------------------------------------------------
__global__ __launch_bounds__(256) void prep_kernel(
    const float* __restrict__ Wdkv, const float* __restrict__ Wk,
    const float* __restrict__ Wq, ushort_t* __restrict__ WcatT)
{
    __shared__ float wk[128 * 64];
    const int t = threadIdx.x;
    for (int i = t; i < 128 * 64; i += 256) wk[i] = Wk[i];
    __syncthreads();
    const int e = blockIdx.x * 256 + t;
    const int l0 = blockIdx.y * 16;
    float acc[16];
    #pragma unroll
    for (int l = 0; l < 16; ++l) acc[l] = 0.f;
    for (int h = 0; h < 128; ++h) {
        float q = Wq[h * NE + e];
        #pragma unroll
        for (int l = 0; l < 16; ++l) acc[l] += q * wk[h * 64 + l0 + l];
    }
    for (int l = 0; l < 16; ++l) WcatT[(64 + l0 + l) * NE + e] = f2bf(acc[l] * SCALE2);
    for (int l = 0; l < 16; ++l) WcatT[(l0 + l) * NE + e] = f2bf(Wdkv[(l0 + l) * NE + e]);
}

// ---------------------------------------------------------------------------
// proj: Y[M,128] = x[M,2048] @ WcatT^T.  BM=64,BN=128,BK=64, 4 waves (2x2).
// Depth-2 ping-pong register prefetch + raw barriers. Fused V epilogue.
// ---------------------------------------------------------------------------
__global__ __launch_bounds__(256) void proj_kernel(
    const float* __restrict__ x, const ushort_t* __restrict__ WcatT,
    const float* __restrict__ Wv,
    float* __restrict__ latent_out, ushort_t* __restrict__ k_bf,
    ushort_t* __restrict__ q_bf, ushort_t* __restrict__ v_t)
{
    __shared__ ushort_t As[2][64 * 64];
    __shared__ ushort_t Bs[2][128 * 64];
    const int tid = threadIdx.x;
    const int w = tid >> 6, lane = tid & 63, lg = lane >> 4, li = lane & 15;
    const int m0 = blockIdx.x * 64;
    const int wm = (w >> 1) * 32, wn = (w & 1) * 64;
    const int srow = tid >> 3, scol = tid & 7;

    f32x4 acc[2][4];
    #pragma unroll
    for (int i = 0; i < 2; ++i)
        #pragma unroll
        for (int j = 0; j < 4; ++j) acc[i][j] = f32x4{0.f, 0.f, 0.f, 0.f};

    f32x4 a0reg[2][2], a1reg[2][2];
    u16x8 b0reg[4], b1reg[4];

#define PLOAD(k0, AR, BR) do { \
    _Pragma("unroll") for (int p = 0; p < 2; ++p) { \
        const float* gp = x + (long)(m0 + srow + 32 * p) * NE + (k0) + scol * 8; \
        AR[p][0] = *reinterpret_cast<const f32x4*>(gp); \
        AR[p][1] = *reinterpret_cast<const f32x4*>(gp + 4); } \
    _Pragma("unroll") for (int p = 0; p < 4; ++p) \
        BR[p] = *reinterpret_cast<const u16x8*>(WcatT + (long)(srow + 32 * p) * NE + (k0) + scol * 8); \
} while (0)

#define PWRITE(AR, BR, buf) do { \
    _Pragma("unroll") for (int p = 0; p < 2; ++p) { \
        u16x8 h; \
        _Pragma("unroll") for (int j = 0; j < 4; ++j) { h[j] = f2bf(AR[p][0][j]); h[4 + j] = f2bf(AR[p][1][j]); } \
        *reinterpret_cast<u16x8*>(reinterpret_cast<char*>(As[buf]) + swz(srow + 32 * p, scol * 16)) = h; } \
    _Pragma("unroll") for (int p = 0; p < 4; ++p) \
        *reinterpret_cast<u16x8*>(reinterpret_cast<char*>(Bs[buf]) + swz(srow + 32 * p, scol * 16)) = BR[p]; \
} while (0)

    auto compute = [&](int buf) {
        #pragma unroll
        for (int c = 0; c < 2; ++c) {
            bf16x8 af[2], bfv[4];
            #pragma unroll
            for (int mf = 0; mf < 2; ++mf)
                af[mf] = *reinterpret_cast<const bf16x8*>(
                    reinterpret_cast<const char*>(As[buf]) + swz(wm + 16 * mf + li, c * 64 + lg * 16));
            #pragma unroll
            for (int nf = 0; nf < 4; ++nf)
                bfv[nf] = *reinterpret_cast<const bf16x8*>(
                    reinterpret_cast<const char*>(Bs[buf]) + swz(wn + 16 * nf + li, c * 64 + lg * 16));
            #pragma unroll
            for (int mf = 0; mf < 2; ++mf)
                #pragma unroll
                for (int nf = 0; nf < 4; ++nf)
                    acc[mf][nf] = __builtin_amdgcn_mfma_f32_16x16x32_bf16(
                        af[mf], bfv[nf], acc[mf][nf], 0, 0, 0);
        }
    };

    PLOAD(0, a0reg, b0reg);
    PLOAD(64, a1reg, b1reg);
    PWRITE(a0reg, b0reg, 0);
    wg_barrier();

    for (int ks = 0; ks < 32; ks += 2) {
        if (ks + 2 < 32) PLOAD((ks + 2) * 64, a0reg, b0reg);
        compute(0);
        PWRITE(a1reg, b1reg, 1);
        wg_barrier();
        if (ks + 3 < 32) PLOAD((ks + 3) * 64, a1reg, b1reg);
        compute(1);
        if (ks + 2 < 32) PWRITE(a0reg, b0reg, 0);
        wg_barrier();
    }

    // ---- epilogue: store latent(f32)+k(bf16)+q(bf16); stage latent bf16 -> As[0]
    const int b = m0 >> 12, s0 = m0 & 4095;
    #pragma unroll
    for (int mf = 0; mf < 2; ++mf) {
        #pragma unroll
        for (int nf = 0; nf < 4; ++nf) {
            int col = wn + 16 * nf + li;
            #pragma unroll
            for (int r = 0; r < 4; ++r) {
                int row = m0 + wm + 16 * mf + 4 * lg + r;
                float v = acc[mf][nf][r];
                if (wn == 0) {
                    latent_out[(long)row * NL + col] = v;
                    k_bf[(long)row * NL + col] = f2bf(v);
                    *reinterpret_cast<ushort_t*>(reinterpret_cast<char*>(As[0]) +
                        swz(wm + 16 * mf + 4 * lg + r, col * 2)) = f2bf(v);
                } else {
                    q_bf[(long)row * NL + (col - 64)] = f2bf(v);
                }
            }
        }
    }
    // stage Wv (f32 -> bf16) -> Bs[0]: [128 dv][64 l], swizzled
    {
        const int r = tid >> 1, hf = tid & 1;
        const float* wp = Wv + r * 64 + hf * 32;
        #pragma unroll
        for (int q = 0; q < 2; ++q) {
            f32x4 w0 = *reinterpret_cast<const f32x4*>(wp + q * 16);
            f32x4 w1 = *reinterpret_cast<const f32x4*>(wp + q * 16 + 4);
            f32x4 w2 = *reinterpret_cast<const f32x4*>(wp + q * 16 + 8);
            f32x4 w3 = *reinterpret_cast<const f32x4*>(wp + q * 16 + 12);
            u16x8 h0, h1;
            #pragma unroll
            for (int j = 0; j < 4; ++j) {
                h0[j] = f2bf(w0[j]); h0[4 + j] = f2bf(w1[j]);
                h1[j] = f2bf(w2[j]); h1[4 + j] = f2bf(w3[j]);
            }
            *reinterpret_cast<u16x8*>(reinterpret_cast<char*>(Bs[0]) + swz(r, hf * 64 + q * 32)) = h0;
            *reinterpret_cast<u16x8*>(reinterpret_cast<char*>(Bs[0]) + swz(r, hf * 64 + q * 32 + 16)) = h1;
        }
    }
    wg_barrier();
    // v GEMM: D[dv][s] = Wv[dv][l] * latent[s][l]; wave w owns dv rows 32w..32w+31
    f32x4 vacc[2][4];
    #pragma unroll
    for (int i = 0; i < 2; ++i)
        #pragma unroll
        for (int j = 0; j < 4; ++j) vacc[i][j] = f32x4{0.f, 0.f, 0.f, 0.f};
    #pragma unroll
    for (int c = 0; c < 2; ++c) {
        bf16x8 af[2], bfv[4];
        #pragma unroll
        for (int mf = 0; mf < 2; ++mf)
            af[mf] = *reinterpret_cast<const bf16x8*>(
                reinterpret_cast<const char*>(Bs[0]) + swz(32 * w + 16 * mf + li, c * 64 + lg * 16));
        #pragma unroll
        for (int nf = 0; nf < 4; ++nf)
            bfv[nf] = *reinterpret_cast<const bf16x8*>(
                reinterpret_cast<const char*>(As[0]) + swz(16 * nf + li, c * 64 + lg * 16));
        #pragma unroll
        for (int mf = 0; mf < 2; ++mf)
            #pragma unroll
            for (int nf = 0; nf < 4; ++nf)
                vacc[mf][nf] = __builtin_amdgcn_mfma_f32_16x16x32_bf16(
                    af[mf], bfv[nf], vacc[mf][nf], 0, 0, 0);
    }
    #pragma unroll
    for (int mf = 0; mf < 2; ++mf)
        #pragma unroll
        for (int nf = 0; nf < 4; ++nf)
            #pragma unroll
            for (int r = 0; r < 4; ++r)
                v_t[(long)(b * 128 + 32 * w + 16 * mf + 4 * lg + r) * NS + s0 + 16 * nf + li] =
                    f2bf(vacc[mf][nf][r]);
}

// ---------------------------------------------------------------------------
// attn: split-KV causal flash attention.
// 1024 blocks = (b, qt, half). Half h processes kv tiles t = h, h+2, ... <= qt
// with its own online (m, l, O~); partials merged exactly by merge_kernel.
// qt permutation balances BOTH consecutive-chunk and mod-8 XCD policies:
// any {p,p+32} slot pair AND any consecutive (2k,2k+1) pair sums to ~63.
// Steady-state softmax has ZERO cross-lane ops (defer-max vote on per-lane
// partial maxima; l kept per-lane, reduced once in the epilogue).
// ---------------------------------------------------------------------------
__global__ __launch_bounds__(256) void attn_kernel(
    const ushort_t* __restrict__ q_bf, const ushort_t* __restrict__ k_bf,
    const ushort_t* __restrict__ v_t, float* __restrict__ Opart,
    float* __restrict__ lpart, float* __restrict__ mpart)
{
    __shared__ ushort_t Ks[2][64 * 64];
    __shared__ ushort_t Vts[2][128 * 64];   // [dv][kv'] permuted columns
    const int tid = threadIdx.x;
    const int w = tid >> 6, lane = tid & 63, lg = lane >> 4, li = lane & 15;
    const int l = blockIdx.x;
    const int b = l & 7;
    const int j = l >> 3;
    const int h = j >> 6;
    const int p_ = j & 63;
    // balanced permutation: k<16: (2k, 62-2k); k>=16: (63-2k', 2k'+1)
    const int k_ = p_ >> 1, e_ = p_ & 1, kk = (k_ & 15) * 2;
    const int qt = (k_ >> 4) ? (e_ ? kk + 1 : 63 - kk) : (e_ ? 62 - kk : kk);
    const int niter = (qt + 2 - h) >> 1;
    const bool hasdiag = ((qt - h) & 1) == 0;
    const int Q0 = qt << 6;
    const int srow = tid >> 3, scol = tid & 7;
    // V permuted column base (bytes): kv' = 32kv4+16kv3+8kv2+4kv5+2kv1+kv0
    const int vc0 = 64 * ((scol >> 1) & 1) + 32 * (scol & 1) + 8 * (scol >> 2);

    // Q fragments (B-operand), pre-scaled at prep time
    const long qrow = (long)b * NS + Q0 + 16 * w + li;
    bf16x8 qf[2];
    qf[0] = *reinterpret_cast<const bf16x8*>(q_bf + qrow * NL + 0 + lg * 8);
    qf[1] = *reinterpret_cast<const bf16x8*>(q_bf + qrow * NL + 32 + lg * 8);

    float m_r = -3.0e38f, l_r = 0.f;   // l_r is a PER-LANE partial
    f32x4 oacc[8];
    #pragma unroll
    for (int n = 0; n < 8; ++n) oacc[n] = f32x4{0.f, 0.f, 0.f, 0.f};

    u16x8 k0reg[2], v0reg[4], k1reg[2], v1reg[4];

#define ALOAD(kv0, KR, VR) do { \
    _Pragma("unroll") for (int p = 0; p < 2; ++p) \
        KR[p] = *reinterpret_cast<const u16x8*>(k_bf + ((long)b * NS + (kv0) + srow + 32 * p) * NL + scol * 8); \
    _Pragma("unroll") for (int p = 0; p < 4; ++p) \
        VR[p] = *reinterpret_cast<const u16x8*>(v_t + (long)(b * 128 + srow + 32 * p) * NS + (kv0) + scol * 8); \
} while (0)

#define AWRITE(KR, VR, buf) do { \
    _Pragma("unroll") for (int p = 0; p < 2; ++p) \
        *reinterpret_cast<u16x8*>(reinterpret_cast<char*>(Ks[buf]) + swz(srow + 32 * p, scol * 16)) = KR[p]; \
    _Pragma("unroll") for (int p = 0; p < 4; ++p) { \
        u16x4 lo = {VR[p][0], VR[p][1], VR[p][2], VR[p][3]}; \
        u16x4 hi = {VR[p][4], VR[p][5], VR[p][6], VR[p][7]}; \
        *reinterpret_cast<u16x4*>(reinterpret_cast<char*>(Vts[buf]) + swz(srow + 32 * p, vc0)) = lo; \
        *reinterpret_cast<u16x4*>(reinterpret_cast<char*>(Vts[buf]) + swz(srow + 32 * p, vc0 + 16)) = hi; \
    } \
} while (0)

    auto compute = [&](int buf, bool diag) {
        const char* Kb = reinterpret_cast<const char*>(Ks[buf]);
        const char* Vb = reinterpret_cast<const char*>(Vts[buf]);
        f32x4 s[4];
        #pragma unroll
        for (int f = 0; f < 4; ++f) s[f] = f32x4{0.f, 0.f, 0.f, 0.f};
        __builtin_amdgcn_s_setprio(1);
        #pragma unroll
        for (int c = 0; c < 2; ++c)
            #pragma unroll
            for (int f = 0; f < 4; ++f) {
                bf16x8 a = *reinterpret_cast<const bf16x8*>(Kb + swz(16 * f + li, c * 64 + lg * 16));
                s[f] = __builtin_amdgcn_mfma_f32_16x16x32_bf16(a, qf[c], s[f], 0, 0, 0);
            }
        __builtin_amdgcn_s_setprio(0);
        // softmax (log2 domain). lane's kv set: 16f+4lg+r; q-row = li.
        float p[16];
        float mx = -3.0e38f;
        #pragma unroll
        for (int f = 0; f < 4; ++f)
            #pragma unroll
            for (int r = 0; r < 4; ++r) {
                float v = s[f][r];
                if (diag && (16 * f + 4 * lg + r) > (16 * w + li)) v = -3.0e38f;
                p[f * 4 + r] = v;
                mx = fmaxf(mx, v);
            }
        // defer-max vote on per-lane PARTIAL maxima (exactly equiv. to row test)
        if (!__all(mx <= m_r + 8.f)) {
            float mxf = fmaxf(mx, __shfl_xor(mx, 16));
            mxf = fmaxf(mxf, __shfl_xor(mxf, 32));
            float m_new = fmaxf(m_r, mxf);
            float corr = fast_exp2(m_r - m_new);
            m_r = m_new;
            l_r *= corr;
            float corrO[4];
            #pragma unroll
            for (int r = 0; r < 4; ++r)
                corrO[r] = __shfl(corr, (lane & 48) | (4 * lg + r));
            #pragma unroll
            for (int n = 0; n < 8; ++n)
                #pragma unroll
                for (int r = 0; r < 4; ++r) oacc[n][r] *= corrO[r];
        }
        float rs = 0.f;
        #pragma unroll
        for (int i = 0; i < 16; ++i) { p[i] = fast_exp2(p[i] - m_r); rs += p[i]; }
        l_r += rs;   // per-lane partial; no cross-lane reduce here
        // pack P to bf16 in-register
        unsigned pw[8];
        #pragma unroll
        for (int f = 0; f < 4; ++f)
            #pragma unroll
            for (int hh = 0; hh < 2; ++hh)
                asm("v_cvt_pk_bf16_f32 %0, %1, %2"
                    : "=v"(pw[2 * f + hh]) : "v"(p[4 * f + 2 * hh]), "v"(p[4 * f + 2 * hh + 1]));
        union { unsigned u[4]; bf16x8 v; } pa0, pa1;
        pa0.u[0] = pw[0]; pa0.u[1] = pw[1]; pa0.u[2] = pw[4]; pa0.u[3] = pw[5];
        pa1.u[0] = pw[2]; pa1.u[1] = pw[3]; pa1.u[2] = pw[6]; pa1.u[3] = pw[7];
        // O~ += P @ V
        __builtin_amdgcn_s_setprio(1);
        #pragma unroll
        for (int c = 0; c < 2; ++c) {
            bf16x8 pa = c ? pa1.v : pa0.v;
            #pragma unroll
            for (int n = 0; n < 8; ++n) {
                bf16x8 vb = *reinterpret_cast<const bf16x8*>(Vb + swz(16 * n + li, c * 64 + lg * 16));
                oacc[n] = __builtin_amdgcn_mfma_f32_16x16x32_bf16(pa, vb, oacc[n], 0, 0, 0);
            }
        }
        __builtin_amdgcn_s_setprio(0);
    };

    if (niter > 0) {
        ALOAD(h * 64, k0reg, v0reg);
        if (niter >= 2) ALOAD((h + 2) * 64, k1reg, v1reg);
        AWRITE(k0reg, v0reg, 0);
        wg_barrier();
        for (int i = 0; i < niter; i += 2) {
            if (i + 2 < niter) ALOAD((h + 2 * (i + 2)) * 64, k0reg, v0reg);
            compute(0, hasdiag && (i == niter - 1));
            if (i + 1 < niter) AWRITE(k1reg, v1reg, 1);
            wg_barrier();
            if (i + 1 >= niter) break;
            if (i + 3 < niter) ALOAD((h + 2 * (i + 3)) * 64, k1reg, v1reg);
            compute(1, hasdiag && (i + 1 == niter - 1));
            if (i + 2 < niter) AWRITE(k0reg, v0reg, 0);
            wg_barrier();
        }
    }

    // epilogue: reduce l across the 4 lane-copies of each q-row, store partials
    l_r += __shfl_xor(l_r, 16);
    l_r += __shfl_xor(l_r, 32);
    const int IB = ((h * NB + b) << 6) + qt;
    if (lane < 16)  {
        lpart[IB * 64 + 16 * w + li] = l_r;
        mpart[IB * 64 + 16 * w + li] = m_r;
    }
    #pragma unroll
    for (int n = 0; n < 8; ++n)
        #pragma unroll
        for (int r = 0; r < 4; ++r)
            Opart[((long)IB * 64 + 16 * w + 4 * lg + r) * NH + 16 * n + li] = oacc[n][r];
}

// ---------------------------------------------------------------------------
// merge: out[row] = (w1*O1 + w2*O2) / (w1*l1 + w2*l2),  wi = 2^(mi - M).
// 512 blocks = (b, qt); thread t: row = t>>2, 64B-contiguous col chunks.
// ---------------------------------------------------------------------------
__global__ __launch_bounds__(256) void merge_kernel(
    const float* __restrict__ Opart, const float* __restrict__ lpart,
    const float* __restrict__ mpart, float* __restrict__ out)
{
    const int blk = blockIdx.x;
    const int b = blk >> 6, qt = blk & 63;
    const int t = threadIdx.x;
    const int row = t >> 2, c0 = (t & 3) * 4;
    const int IB1 = (b << 6) + qt;
    const int IB2 = ((NB + b) << 6) + qt;
    const long r1 = (long)IB1 * 64 + row, r2 = (long)IB2 * 64 + row;
    float l1 = lpart[r1], m1 = mpart[r1];
    float l2 = lpart[r2], m2 = mpart[r2];
    float M = fmaxf(m1, m2);
    float w1 = fast_exp2(m1 - M), w2 = fast_exp2(m2 - M);
    float inv = 1.f / (w1 * l1 + w2 * l2);
    float a1 = w1 * inv, a2 = w2 * inv;
    const float* o1 = Opart + r1 * NH;
    const float* o2 = Opart + r2 * NH;
    float* op = out + ((long)b * NS + qt * 64 + row) * NH;
    #pragma unroll
    for (int jj = 0; jj < 8; ++jj) {
        int col = c0 + 16 * jj;
        f32x4 A = *reinterpret_cast<const f32x4*>(o1 + col);
        f32x4 Bv = *reinterpret_cast<const f32x4*>(o2 + col);
        f32x4 R;
        #pragma unroll
        for (int q = 0; q < 4; ++q) R[q] = A[q] * a1 + Bv[q] * a2;
        *reinterpret_cast<f32x4*>(op + col) = R;
    }
}

// ---------------------------------------------------------------------------
extern "C" void kernel_launch(void* const* d_in, const int* in_sizes, int n_in,
                              void* d_out, int out_size, void* d_ws, size_t ws_size,
                              hipStream_t stream) {
    const float* x    = (const float*)d_in[0];
    const float* Wdkv = (const float*)d_in[1];
    const float* Wk   = (const float*)d_in[2];
    const float* Wv   = (const float*)d_in[3];
    const float* Wq   = (const float*)d_in[4];

    float* out = (float*)d_out;
    float* latent_out = out + (long)NM * NH;   // output 1 follows output 0

    // workspace layout (~51.4 MB)
    ushort_t* WcatT = (ushort_t*)d_ws;                 // 512 KB
    ushort_t* q_bf  = WcatT + 128 * NE;                // 4 MB
    ushort_t* k_bf  = q_bf + (long)NM * NL;            // 4 MB
    ushort_t* v_t   = k_bf + (long)NM * NL;            // 8 MB (transposed V)
    float* Opart = (float*)(v_t + (long)NM * NH);      // 2*8*64*64*128 f32 = 33.5 MB
    float* lpart = Opart + (long)2 * NB * NQT * 64 * NH;   // 256 KB
    float* mpart = lpart + 2 * NB * NQT * 64;              // 256 KB

    hipLaunchKernelGGL(prep_kernel, dim3(NE / 256, 4), dim3(256), 0, stream, Wdkv, Wk, Wq, WcatT);
    hipLaunchKernelGGL(proj_kernel, dim3(NM / 64), dim3(256), 0, stream,
                       x, WcatT, Wv, latent_out, k_bf, q_bf, v_t);
    hipLaunchKernelGGL(attn_kernel, dim3(1024), dim3(256), 0, stream,
                       q_bf, k_bf, v_t, Opart, lpart, mpart);
    hipLaunchKernelGGL(merge_kernel, dim3(NB * NQT), dim3(256), 0, stream,
                       Opart, lpart, mpart, out);
}

// Round 7
// 142.825 us; speedup vs baseline: 3.2834x; 1.1279x over previous
//
#include <hip/hip_runtime.h>
#include <hip/hip_bf16.h>

#define NB 8
#define NS 4096
#define NE 2048
#define NL 64
#define NH 128
#define NM (NB*NS)
#define NQT (NS/64)   // 64 q-tiles per batch

typedef unsigned short ushort_t;
typedef __attribute__((ext_vector_type(4))) float f32x4;
typedef __attribute__((ext_vector_type(8))) __bf16 bf16x8;
typedef __attribute__((ext_vector_type(8))) unsigned short u16x8;
typedef __attribute__((ext_vector_type(4))) unsigned short u16x4;

// 128^-0.5 * log2(e): folded into absorbed-q weights so attn uses exp2 directly
#define SCALE2 0.1275174537f

__device__ __forceinline__ float fast_exp2(float x) {
    return __builtin_amdgcn_exp2f(x);   // v_exp_f32: D = 2^S0
}

__device__ __forceinline__ unsigned short f2bf(float f) {
    union { float f; unsigned u; } v; v.f = f;
    unsigned u = v.u + 0x7fffu + ((v.u >> 16) & 1u);
    return (unsigned short)(u >> 16);
}

// XOR swizzle for 128-byte-stride LDS tiles (G4: fixes 16/32-way ds_read_b128 conflicts)
__device__ __forceinline__ int swz(int row, int colbyte) {
    return (row * 128 + colbyte) ^ ((row & 7) << 4);
}

// Raw barrier: LDS visibility only — does NOT drain vmcnt (T4).
__device__ __forceinline__ void wg_barrier() {
    asm volatile("s_waitcnt lgkmcnt(0)" ::: "memory");
    __builtin_amdgcn_s_barrier();
    __builtin_amdgcn_sched_barrier(0);
}

// ---------------------------------------------------------------------------
// prep: WcatT[128][2048] bf16.  rows 0..63 = W_dkv, rows 64..127 = absorbed^T * SCALE2
// ---------------------------------------------------------------------------
__global__ __launch_bounds__(256) void prep_kernel(
    const float* __restrict__ Wdkv, const float* __restrict__ Wk,
    const float* __restrict__ Wq, ushort_t* __restrict__ WcatT)
{
    __shared__ float wk[128 * 64];
    const int t = threadIdx.x;
    for (int i = t; i < 128 * 64; i += 256) wk[i] = Wk[i];
    __syncthreads();
    const int e = blockIdx.x * 256 + t;
    const int l0 = blockIdx.y * 16;
    float acc[16];
    #pragma unroll
    for (int l = 0; l < 16; ++l) acc[l] = 0.f;
    for (int h = 0; h < 128; ++h) {
        float q = Wq[h * NE + e];
        #pragma unroll
        for (int l = 0; l < 16; ++l) acc[l] += q * wk[h * 64 + l0 + l];
    }
    for (int l = 0; l < 16; ++l) WcatT[(64 + l0 + l) * NE + e] = f2bf(acc[l] * SCALE2);
    for (int l = 0; l < 16; ++l) WcatT[(l0 + l) * NE + e] = f2bf(Wdkv[(l0 + l) * NE + e]);
}

// ---------------------------------------------------------------------------
// proj: Y[M,128] = x[M,2048] @ WcatT^T.  BM=64,BN=128,BK=64, 4 waves (2x2).
// Depth-2 ping-pong register prefetch + raw barriers.
// Epilogue: latent(f32) + k(bf16) + q(bf16) + kt = latent^T (bf16, via
// identity-fragment MFMA transpose of the staged latent tile).
// ---------------------------------------------------------------------------
__global__ __launch_bounds__(256) void proj_kernel(
    const float* __restrict__ x, const ushort_t* __restrict__ WcatT,
    float* __restrict__ latent_out, ushort_t* __restrict__ k_bf,
    ushort_t* __restrict__ q_bf, ushort_t* __restrict__ kt)
{
    __shared__ ushort_t As[2][64 * 64];
    __shared__ ushort_t Bs[2][128 * 64];
    const int tid = threadIdx.x;
    const int w = tid >> 6, lane = tid & 63, lg = lane >> 4, li = lane & 15;
    const int m0 = blockIdx.x * 64;
    const int wm = (w >> 1) * 32, wn = (w & 1) * 64;
    const int srow = tid >> 3, scol = tid & 7;

    f32x4 acc[2][4];
    #pragma unroll
    for (int i = 0; i < 2; ++i)
        #pragma unroll
        for (int j = 0; j < 4; ++j) acc[i][j] = f32x4{0.f, 0.f, 0.f, 0.f};

    f32x4 a0reg[2][2], a1reg[2][2];
    u16x8 b0reg[4], b1reg[4];

#define PLOAD(k0, AR, BR) do { \
    _Pragma("unroll") for (int p = 0; p < 2; ++p) { \
        const float* gp = x + (long)(m0 + srow + 32 * p) * NE + (k0) + scol * 8; \
        AR[p][0] = *reinterpret_cast<const f32x4*>(gp); \
        AR[p][1] = *reinterpret_cast<const f32x4*>(gp + 4); } \
    _Pragma("unroll") for (int p = 0; p < 4; ++p) \
        BR[p] = *reinterpret_cast<const u16x8*>(WcatT + (long)(srow + 32 * p) * NE + (k0) + scol * 8); \
} while (0)

#define PWRITE(AR, BR, buf) do { \
    _Pragma("unroll") for (int p = 0; p < 2; ++p) { \
        u16x8 h; \
        _Pragma("unroll") for (int j = 0; j < 4; ++j) { h[j] = f2bf(AR[p][0][j]); h[4 + j] = f2bf(AR[p][1][j]); } \
        *reinterpret_cast<u16x8*>(reinterpret_cast<char*>(As[buf]) + swz(srow + 32 * p, scol * 16)) = h; } \
    _Pragma("unroll") for (int p = 0; p < 4; ++p) \
        *reinterpret_cast<u16x8*>(reinterpret_cast<char*>(Bs[buf]) + swz(srow + 32 * p, scol * 16)) = BR[p]; \
} while (0)

    auto compute = [&](int buf) {
        #pragma unroll
        for (int c = 0; c < 2; ++c) {
            bf16x8 af[2], bfv[4];
            #pragma unroll
            for (int mf = 0; mf < 2; ++mf)
                af[mf] = *reinterpret_cast<const bf16x8*>(
                    reinterpret_cast<const char*>(As[buf]) + swz(wm + 16 * mf + li, c * 64 + lg * 16));
            #pragma unroll
            for (int nf = 0; nf < 4; ++nf)
                bfv[nf] = *reinterpret_cast<const bf16x8*>(
                    reinterpret_cast<const char*>(Bs[buf]) + swz(wn + 16 * nf + li, c * 64 + lg * 16));
            #pragma unroll
            for (int mf = 0; mf < 2; ++mf)
                #pragma unroll
                for (int nf = 0; nf < 4; ++nf)
                    acc[mf][nf] = __builtin_amdgcn_mfma_f32_16x16x32_bf16(
                        af[mf], bfv[nf], acc[mf][nf], 0, 0, 0);
        }
    };

    PLOAD(0, a0reg, b0reg);
    PLOAD(64, a1reg, b1reg);
    PWRITE(a0reg, b0reg, 0);
    wg_barrier();

    for (int ks = 0; ks < 32; ks += 2) {
        if (ks + 2 < 32) PLOAD((ks + 2) * 64, a0reg, b0reg);
        compute(0);
        PWRITE(a1reg, b1reg, 1);
        wg_barrier();
        if (ks + 3 < 32) PLOAD((ks + 3) * 64, a1reg, b1reg);
        compute(1);
        if (ks + 2 < 32) PWRITE(a0reg, b0reg, 0);
        wg_barrier();
    }

    // ---- epilogue: store latent(f32)+k(bf16)+q(bf16); stage latent bf16 -> As[0]
    const int b = m0 >> 12, s0 = m0 & 4095;
    #pragma unroll
    for (int mf = 0; mf < 2; ++mf) {
        #pragma unroll
        for (int nf = 0; nf < 4; ++nf) {
            int col = wn + 16 * nf + li;
            #pragma unroll
            for (int r = 0; r < 4; ++r) {
                int row = m0 + wm + 16 * mf + 4 * lg + r;
                float v = acc[mf][nf][r];
                if (wn == 0) {
                    latent_out[(long)row * NL + col] = v;
                    k_bf[(long)row * NL + col] = f2bf(v);
                    *reinterpret_cast<ushort_t*>(reinterpret_cast<char*>(As[0]) +
                        swz(wm + 16 * mf + 4 * lg + r, col * 2)) = f2bf(v);
                } else {
                    q_bf[(long)row * NL + (col - 64)] = f2bf(v);
                }
            }
        }
    }
    wg_barrier();
    // kt-GEMM: kt[l][s] = latent^T via A = identity fragment.
    // Wave w owns kt rows 16w..16w+15; c = w>>1 selects the k-half.
    // A_local[li][lg*8+j] = 1 iff lg == (li>>3)+2*(w&1) and j == (li&7).
    union { u16x8 u; bf16x8 v; } iu;
    #pragma unroll
    for (int j = 0; j < 8; ++j)
        iu.u[j] = (lg == (li >> 3) + 2 * (w & 1) && (li & 7) == j)
                      ? (ushort_t)0x3F80 : (ushort_t)0;
    const int ckt = w >> 1;
    f32x4 ktacc[4];
    #pragma unroll
    for (int nf = 0; nf < 4; ++nf) {
        bf16x8 bfv = *reinterpret_cast<const bf16x8*>(
            reinterpret_cast<const char*>(As[0]) + swz(16 * nf + li, ckt * 64 + lg * 16));
        ktacc[nf] = __builtin_amdgcn_mfma_f32_16x16x32_bf16(
            iu.v, bfv, f32x4{0.f, 0.f, 0.f, 0.f}, 0, 0, 0);
    }
    #pragma unroll
    for (int nf = 0; nf < 4; ++nf)
        #pragma unroll
        for (int r = 0; r < 4; ++r)
            kt[(long)(b * 64 + 16 * w + 4 * lg + r) * NS + s0 + 16 * nf + li] =
                f2bf(ktacc[nf][r]);
}

// ---------------------------------------------------------------------------
// attn: split-KV causal flash attention IN LATENT SPACE (dv = 64).
// O_lat = softmax(QK^T) @ latent; the Wv projection happens in merge.
// PV B-operand = kt tiles (latent^T), staged with the validated kv-permuted
// layout so P never leaves registers. 1024 blocks = (b, qt-perm, half).
// ---------------------------------------------------------------------------
__global__ __launch_bounds__(256) void attn_kernel(
    const ushort_t* __restrict__ q_bf, const ushort_t* __restrict__ k_bf,
    const ushort_t* __restrict__ kt, float* __restrict__ Opart,
    float* __restrict__ lpart, float* __restrict__ mpart)
{
    __shared__ ushort_t Ks[2][64 * 64];
    __shared__ ushort_t KTs[2][64 * 64];   // [l][kv'] permuted columns
    const int tid = threadIdx.x;
    const int w = tid >> 6, lane = tid & 63, lg = lane >> 4, li = lane & 15;
    const int l = blockIdx.x;
    const int b = l & 7;
    const int j = l >> 3;
    const int h = j >> 6;
    const int p_ = j & 63;
    // balanced permutation: k<16: (2k, 62-2k); k>=16: (63-2k', 2k'+1)
    const int k_ = p_ >> 1, e_ = p_ & 1, kk = (k_ & 15) * 2;
    const int qt = (k_ >> 4) ? (e_ ? kk + 1 : 63 - kk) : (e_ ? 62 - kk : kk);
    const int niter = (qt + 2 - h) >> 1;
    const bool hasdiag = ((qt - h) & 1) == 0;
    const int Q0 = qt << 6;
    const int srow = tid >> 3, scol = tid & 7;
    // permuted column base (bytes): kv' = 32kv4+16kv3+8kv2+4kv5+2kv1+kv0
    const int vc0 = 64 * ((scol >> 1) & 1) + 32 * (scol & 1) + 8 * (scol >> 2);

    // Q fragments (B-operand), pre-scaled at prep time
    const long qrow = (long)b * NS + Q0 + 16 * w + li;
    bf16x8 qf[2];
    qf[0] = *reinterpret_cast<const bf16x8*>(q_bf + qrow * NL + 0 + lg * 8);
    qf[1] = *reinterpret_cast<const bf16x8*>(q_bf + qrow * NL + 32 + lg * 8);

    float m_r = -3.0e38f, l_r = 0.f;   // l_r is a PER-LANE partial
    f32x4 oacc[4];
    #pragma unroll
    for (int n = 0; n < 4; ++n) oacc[n] = f32x4{0.f, 0.f, 0.f, 0.f};

    u16x8 k0reg[2], t0reg[2], k1reg[2], t1reg[2];

#define ALOAD(kv0, KR, TR) do { \
    _Pragma("unroll") for (int p = 0; p < 2; ++p) \
        KR[p] = *reinterpret_cast<const u16x8*>(k_bf + ((long)b * NS + (kv0) + srow + 32 * p) * NL + scol * 8); \
    _Pragma("unroll") for (int p = 0; p < 2; ++p) \
        TR[p] = *reinterpret_cast<const u16x8*>(kt + (long)(b * 64 + srow + 32 * p) * NS + (kv0) + scol * 8); \
} while (0)

#define AWRITE(KR, TR, buf) do { \
    _Pragma("unroll") for (int p = 0; p < 2; ++p) \
        *reinterpret_cast<u16x8*>(reinterpret_cast<char*>(Ks[buf]) + swz(srow + 32 * p, scol * 16)) = KR[p]; \
    _Pragma("unroll") for (int p = 0; p < 2; ++p) { \
        u16x4 lo = {TR[p][0], TR[p][1], TR[p][2], TR[p][3]}; \
        u16x4 hi = {TR[p][4], TR[p][5], TR[p][6], TR[p][7]}; \
        *reinterpret_cast<u16x4*>(reinterpret_cast<char*>(KTs[buf]) + swz(srow + 32 * p, vc0)) = lo; \
        *reinterpret_cast<u16x4*>(reinterpret_cast<char*>(KTs[buf]) + swz(srow + 32 * p, vc0 + 16)) = hi; \
    } \
} while (0)

    auto compute = [&](int buf, bool diag) {
        const char* Kb = reinterpret_cast<const char*>(Ks[buf]);
        const char* Tb = reinterpret_cast<const char*>(KTs[buf]);
        f32x4 s[4];
        #pragma unroll
        for (int f = 0; f < 4; ++f) s[f] = f32x4{0.f, 0.f, 0.f, 0.f};
        __builtin_amdgcn_s_setprio(1);
        #pragma unroll
        for (int c = 0; c < 2; ++c)
            #pragma unroll
            for (int f = 0; f < 4; ++f) {
                bf16x8 a = *reinterpret_cast<const bf16x8*>(Kb + swz(16 * f + li, c * 64 + lg * 16));
                s[f] = __builtin_amdgcn_mfma_f32_16x16x32_bf16(a, qf[c], s[f], 0, 0, 0);
            }
        __builtin_amdgcn_s_setprio(0);
        // softmax (log2 domain). lane's kv set: 16f+4lg+r; q-row = li.
        float p[16];
        float mx = -3.0e38f;
        #pragma unroll
        for (int f = 0; f < 4; ++f)
            #pragma unroll
            for (int r = 0; r < 4; ++r) {
                float v = s[f][r];
                if (diag && (16 * f + 4 * lg + r) > (16 * w + li)) v = -3.0e38f;
                p[f * 4 + r] = v;
                mx = fmaxf(mx, v);
            }
        // defer-max vote on per-lane PARTIAL maxima (exactly equiv. to row test)
        if (!__all(mx <= m_r + 8.f)) {
            float mxf = fmaxf(mx, __shfl_xor(mx, 16));
            mxf = fmaxf(mxf, __shfl_xor(mxf, 32));
            float m_new = fmaxf(m_r, mxf);
            float corr = fast_exp2(m_r - m_new);
            m_r = m_new;
            l_r *= corr;
            float corrO[4];
            #pragma unroll
            for (int r = 0; r < 4; ++r)
                corrO[r] = __shfl(corr, (lane & 48) | (4 * lg + r));
            #pragma unroll
            for (int n = 0; n < 4; ++n)
                #pragma unroll
                for (int r = 0; r < 4; ++r) oacc[n][r] *= corrO[r];
        }
        float rs = 0.f;
        #pragma unroll
        for (int i = 0; i < 16; ++i) { p[i] = fast_exp2(p[i] - m_r); rs += p[i]; }
        l_r += rs;   // per-lane partial; no cross-lane reduce here
        // pack P to bf16 in-register
        unsigned pw[8];
        #pragma unroll
        for (int f = 0; f < 4; ++f)
            #pragma unroll
            for (int hh = 0; hh < 2; ++hh)
                asm("v_cvt_pk_bf16_f32 %0, %1, %2"
                    : "=v"(pw[2 * f + hh]) : "v"(p[4 * f + 2 * hh]), "v"(p[4 * f + 2 * hh + 1]));
        union { unsigned u[4]; bf16x8 v; } pa0, pa1;
        pa0.u[0] = pw[0]; pa0.u[1] = pw[1]; pa0.u[2] = pw[4]; pa0.u[3] = pw[5];
        pa1.u[0] = pw[2]; pa1.u[1] = pw[3]; pa1.u[2] = pw[6]; pa1.u[3] = pw[7];
        // O_lat += P @ latent  (B = kt tile, kv-permuted)
        __builtin_amdgcn_s_setprio(1);
        #pragma unroll
        for (int c = 0; c < 2; ++c) {
            bf16x8 pa = c ? pa1.v : pa0.v;
            #pragma unroll
            for (int n = 0; n < 4; ++n) {
                bf16x8 vb = *reinterpret_cast<const bf16x8*>(Tb + swz(16 * n + li, c * 64 + lg * 16));
                oacc[n] = __builtin_amdgcn_mfma_f32_16x16x32_bf16(pa, vb, oacc[n], 0, 0, 0);
            }
        }
        __builtin_amdgcn_s_setprio(0);
    };

    if (niter > 0) {
        ALOAD(h * 64, k0reg, t0reg);
        if (niter >= 2) ALOAD((h + 2) * 64, k1reg, t1reg);
        AWRITE(k0reg, t0reg, 0);
        wg_barrier();
        for (int i = 0; i < niter; i += 2) {
            if (i + 2 < niter) ALOAD((h + 2 * (i + 2)) * 64, k0reg, t0reg);
            compute(0, hasdiag && (i == niter - 1));
            if (i + 1 < niter) AWRITE(k1reg, t1reg, 1);
            wg_barrier();
            if (i + 1 >= niter) break;
            if (i + 3 < niter) ALOAD((h + 2 * (i + 3)) * 64, k1reg, t1reg);
            compute(1, hasdiag && (i + 1 == niter - 1));
            if (i + 2 < niter) AWRITE(k0reg, t0reg, 0);
            wg_barrier();
        }
    }

    // epilogue: reduce l across the 4 lane-copies of each q-row, store partials
    l_r += __shfl_xor(l_r, 16);
    l_r += __shfl_xor(l_r, 32);
    const int IB = ((h * NB + b) << 6) + qt;
    if (lane < 16)  {
        lpart[IB * 64 + 16 * w + li] = l_r;
        mpart[IB * 64 + 16 * w + li] = m_r;
    }
    #pragma unroll
    for (int n = 0; n < 4; ++n)
        #pragma unroll
        for (int r = 0; r < 4; ++r)
            Opart[((long)IB * 64 + 16 * w + 4 * lg + r) * NL + 16 * n + li] = oacc[n][r];
}

// ---------------------------------------------------------------------------
// merge: exact split-KV combine in latent space, then out = O_lat @ Wv^T via
// MFMA (4 waves, identical fragment pattern to proj's GEMM). 512 blocks=(b,qt).
// ---------------------------------------------------------------------------
__global__ __launch_bounds__(256) void merge_kernel(
    const float* __restrict__ Opart, const float* __restrict__ lpart,
    const float* __restrict__ mpart, const float* __restrict__ Wv,
    float* __restrict__ out)
{
    __shared__ ushort_t Ms[64 * 64];    // merged O_lat bf16, swizzled
    __shared__ ushort_t Wvs[128 * 64];  // Wv bf16, swizzled
    __shared__ float Os[64 * 132];      // out stage [s][dv]
    const int blk = blockIdx.x;
    const int b = blk >> 6, qt = blk & 63;
    const int tid = threadIdx.x;
    const int w = tid >> 6, lane = tid & 63, lg = lane >> 4, li = lane & 15;

    // stage Wv (f32 -> bf16) -> Wvs: [128 dv][64 l], swizzled
    {
        const int r = tid >> 1, hf = tid & 1;
        const float* wp = Wv + r * 64 + hf * 32;
        #pragma unroll
        for (int q = 0; q < 2; ++q) {
            f32x4 w0 = *reinterpret_cast<const f32x4*>(wp + q * 16);
            f32x4 w1 = *reinterpret_cast<const f32x4*>(wp + q * 16 + 4);
            f32x4 w2 = *reinterpret_cast<const f32x4*>(wp + q * 16 + 8);
            f32x4 w3 = *reinterpret_cast<const f32x4*>(wp + q * 16 + 12);
            u16x8 h0, h1;
            #pragma unroll
            for (int jj = 0; jj < 4; ++jj) {
                h0[jj] = f2bf(w0[jj]); h0[4 + jj] = f2bf(w1[jj]);
                h1[jj] = f2bf(w2[jj]); h1[4 + jj] = f2bf(w3[jj]);
            }
            *reinterpret_cast<u16x8*>(reinterpret_cast<char*>(Wvs) + swz(r, hf * 64 + q * 32)) = h0;
            *reinterpret_cast<u16x8*>(reinterpret_cast<char*>(Wvs) + swz(r, hf * 64 + q * 32 + 16)) = h1;
        }
    }
    // merge partials -> Ms (bf16, swizzled)
    {
        const int r = tid >> 2, c0 = (tid & 3) * 16;
        const long L1 = ((long)((b << 6) + qt)) * 64 + r;
        const long L2 = ((long)(((NB + b) << 6) + qt)) * 64 + r;
        float l1 = lpart[L1], m1 = mpart[L1];
        float l2 = lpart[L2], m2 = mpart[L2];
        float M = fmaxf(m1, m2);
        float w1 = fast_exp2(m1 - M), w2 = fast_exp2(m2 - M);
        float inv = 1.f / (w1 * l1 + w2 * l2);
        float a1 = w1 * inv, a2 = w2 * inv;
        const float* o1 = Opart + L1 * NL;
        const float* o2 = Opart + L2 * NL;
        #pragma unroll
        for (int q = 0; q < 4; ++q) {
            int col = c0 + q * 4;
            f32x4 A = *reinterpret_cast<const f32x4*>(o1 + col);
            f32x4 Bv = *reinterpret_cast<const f32x4*>(o2 + col);
            u16x4 hh;
            #pragma unroll
            for (int k = 0; k < 4; ++k) hh[k] = f2bf(A[k] * a1 + Bv[k] * a2);
            *reinterpret_cast<u16x4*>(reinterpret_cast<char*>(Ms) + swz(r, col * 2)) = hh;
        }
    }
    __syncthreads();
    // MFMA: D[dv][s] = Wv[dv][l] * O_lat^T[l][s]; wave w owns dv rows 32w..32w+31
    f32x4 vacc[2][4];
    #pragma unroll
    for (int i = 0; i < 2; ++i)
        #pragma unroll
        for (int jj = 0; jj < 4; ++jj) vacc[i][jj] = f32x4{0.f, 0.f, 0.f, 0.f};
    #pragma unroll
    for (int c = 0; c < 2; ++c) {
        bf16x8 af[2], bfv[4];
        #pragma unroll
        for (int mf = 0; mf < 2; ++mf)
            af[mf] = *reinterpret_cast<const bf16x8*>(
                reinterpret_cast<const char*>(Wvs) + swz(32 * w + 16 * mf + li, c * 64 + lg * 16));
        #pragma unroll
        for (int nf = 0; nf < 4; ++nf)
            bfv[nf] = *reinterpret_cast<const bf16x8*>(
                reinterpret_cast<const char*>(Ms) + swz(16 * nf + li, c * 64 + lg * 16));
        #pragma unroll
        for (int mf = 0; mf < 2; ++mf)
            #pragma unroll
            for (int nf = 0; nf < 4; ++nf)
                vacc[mf][nf] = __builtin_amdgcn_mfma_f32_16x16x32_bf16(
                    af[mf], bfv[nf], vacc[mf][nf], 0, 0, 0);
    }
    // stage transposed: Os[s][dv]
    #pragma unroll
    for (int mf = 0; mf < 2; ++mf)
        #pragma unroll
        for (int nf = 0; nf < 4; ++nf)
            #pragma unroll
            for (int r = 0; r < 4; ++r)
                Os[(16 * nf + li) * 132 + 32 * w + 16 * mf + 4 * lg + r] = vacc[mf][nf][r];
    __syncthreads();
    // coalesced f32x4 writes
    {
        const int r = tid >> 2, cb = (tid & 3) * 32;
        float* op = out + ((long)b * NS + qt * 64 + r) * NH + cb;
        const float* sp = Os + r * 132 + cb;
        #pragma unroll
        for (int q = 0; q < 8; ++q)
            *reinterpret_cast<f32x4*>(op + 4 * q) = *reinterpret_cast<const f32x4*>(sp + 4 * q);
    }
}

// ---------------------------------------------------------------------------
extern "C" void kernel_launch(void* const* d_in, const int* in_sizes, int n_in,
                              void* d_out, int out_size, void* d_ws, size_t ws_size,
                              hipStream_t stream) {
    const float* x    = (const float*)d_in[0];
    const float* Wdkv = (const float*)d_in[1];
    const float* Wk   = (const float*)d_in[2];
    const float* Wv   = (const float*)d_in[3];
    const float* Wq   = (const float*)d_in[4];

    float* out = (float*)d_out;
    float* latent_out = out + (long)NM * NH;   // output 1 follows output 0

    // workspace layout (~30 MB)
    ushort_t* WcatT = (ushort_t*)d_ws;                 // 512 KB
    ushort_t* q_bf  = WcatT + 128 * NE;                // 4 MB
    ushort_t* k_bf  = q_bf + (long)NM * NL;            // 4 MB
    ushort_t* kt    = k_bf + (long)NM * NL;            // 4 MB (latent^T)
    float* Opart = (float*)(kt + (long)NM * NL);       // 2*8*64*64*64 f32 = 16.8 MB
    float* lpart = Opart + (long)2 * NB * NQT * 64 * NL;   // 256 KB
    float* mpart = lpart + 2 * NB * NQT * 64;              // 256 KB

    hipLaunchKernelGGL(prep_kernel, dim3(NE / 256, 4), dim3(256), 0, stream, Wdkv, Wk, Wq, WcatT);
    hipLaunchKernelGGL(proj_kernel, dim3(NM / 64), dim3(256), 0, stream,
                       x, WcatT, latent_out, k_bf, q_bf, kt);
    hipLaunchKernelGGL(attn_kernel, dim3(1024), dim3(256), 0, stream,
                       q_bf, k_bf, kt, Opart, lpart, mpart);
    hipLaunchKernelGGL(merge_kernel, dim3(NB * NQT), dim3(256), 0, stream,
                       Opart, lpart, mpart, Wv, out);
}

// Round 8
// 134.266 us; speedup vs baseline: 3.4927x; 1.0637x over previous
//
#include <hip/hip_runtime.h>
#include <hip/hip_bf16.h>

#define NB 8
#define NS 4096
#define NE 2048
#define NL 64
#define NH 128
#define NM (NB*NS)

typedef unsigned short ushort_t;
typedef __attribute__((ext_vector_type(4))) float f32x4;
typedef __attribute__((ext_vector_type(8))) __bf16 bf16x8;
typedef __attribute__((ext_vector_type(8))) unsigned short u16x8;
typedef __attribute__((ext_vector_type(4))) unsigned short u16x4;

// 128^-0.5 * log2(e): folded into absorbed-q weights so attn uses exp2 directly
#define SCALE2 0.1275174537f

__device__ __forceinline__ float fast_exp2(float x) {
    return __builtin_amdgcn_exp2f(x);   // v_exp_f32: D = 2^S0
}

__device__ __forceinline__ unsigned short f2bf(float f) {
    union { float f; unsigned u; } v; v.f = f;
    unsigned u = v.u + 0x7fffu + ((v.u >> 16) & 1u);
    return (unsigned short)(u >> 16);
}

__device__ __forceinline__ float bf2f(ushort_t u) {
    union { unsigned u; float f; } v; v.u = (unsigned)u << 16; return v.f;
}

// XOR swizzle for 128-byte-stride LDS tiles (G4)
__device__ __forceinline__ int swz(int row, int colbyte) {
    return (row * 128 + colbyte) ^ ((row & 7) << 4);
}

// Raw barrier: LDS visibility only — does NOT drain vmcnt (T4).
__device__ __forceinline__ void wg_barrier() {
    asm volatile("s_waitcnt lgkmcnt(0)" ::: "memory");
    __builtin_amdgcn_s_barrier();
    __builtin_amdgcn_sched_barrier(0);
}

// ---------------------------------------------------------------------------
// prep: WcatT[128][2048] bf16.  rows 0..63 = W_dkv, rows 64..127 = absorbed^T * SCALE2
// ---------------------------------------------------------------------------
__global__ __launch_bounds__(256) void prep_kernel(
    const float* __restrict__ Wdkv, const float* __restrict__ Wk,
    const float* __restrict__ Wq, ushort_t* __restrict__ WcatT)
{
    __shared__ float wk[128 * 64];
    const int t = threadIdx.x;
    for (int i = t; i < 128 * 64; i += 256) wk[i] = Wk[i];
    __syncthreads();
    const int e = blockIdx.x * 256 + t;
    const int l0 = blockIdx.y * 16;
    float acc[16];
    #pragma unroll
    for (int l = 0; l < 16; ++l) acc[l] = 0.f;
    for (int h = 0; h < 128; ++h) {
        float q = Wq[h * NE + e];
        #pragma unroll
        for (int l = 0; l < 16; ++l) acc[l] += q * wk[h * 64 + l0 + l];
    }
    for (int l = 0; l < 16; ++l) WcatT[(64 + l0 + l) * NE + e] = f2bf(acc[l] * SCALE2);
    for (int l = 0; l < 16; ++l) WcatT[(l0 + l) * NE + e] = f2bf(Wdkv[(l0 + l) * NE + e]);
}

// ---------------------------------------------------------------------------
// proj: Y[M,128] = x[M,2048] @ WcatT^T.  BM=64,BN=128,BK=64, 4 waves (2x2).
// Depth-2 ping-pong register prefetch + raw barriers.
// Epilogue: latent(f32) + k(bf16) + q(bf16) + kt = latent^T (identity MFMA).
// ---------------------------------------------------------------------------
__global__ __launch_bounds__(256) void proj_kernel(
    const float* __restrict__ x, const ushort_t* __restrict__ WcatT,
    float* __restrict__ latent_out, ushort_t* __restrict__ k_bf,
    ushort_t* __restrict__ q_bf, ushort_t* __restrict__ kt)
{
    __shared__ ushort_t As[2][64 * 64];
    __shared__ ushort_t Bs[2][128 * 64];
    const int tid = threadIdx.x;
    const int w = tid >> 6, lane = tid & 63, lg = lane >> 4, li = lane & 15;
    const int m0 = blockIdx.x * 64;
    const int wm = (w >> 1) * 32, wn = (w & 1) * 64;
    const int srow = tid >> 3, scol = tid & 7;

    f32x4 acc[2][4];
    #pragma unroll
    for (int i = 0; i < 2; ++i)
        #pragma unroll
        for (int j = 0; j < 4; ++j) acc[i][j] = f32x4{0.f, 0.f, 0.f, 0.f};

    f32x4 a0reg[2][2], a1reg[2][2];
    u16x8 b0reg[4], b1reg[4];

#define PLOAD(k0, AR, BR) do { \
    _Pragma("unroll") for (int p = 0; p < 2; ++p) { \
        const float* gp = x + (long)(m0 + srow + 32 * p) * NE + (k0) + scol * 8; \
        AR[p][0] = *reinterpret_cast<const f32x4*>(gp); \
        AR[p][1] = *reinterpret_cast<const f32x4*>(gp + 4); } \
    _Pragma("unroll") for (int p = 0; p < 4; ++p) \
        BR[p] = *reinterpret_cast<const u16x8*>(WcatT + (long)(srow + 32 * p) * NE + (k0) + scol * 8); \
} while (0)

#define PWRITE(AR, BR, buf) do { \
    _Pragma("unroll") for (int p = 0; p < 2; ++p) { \
        union { unsigned uw[4]; u16x8 v; } hu; \
        asm("v_cvt_pk_bf16_f32 %0, %1, %2" : "=v"(hu.uw[0]) : "v"(AR[p][0][0]), "v"(AR[p][0][1])); \
        asm("v_cvt_pk_bf16_f32 %0, %1, %2" : "=v"(hu.uw[1]) : "v"(AR[p][0][2]), "v"(AR[p][0][3])); \
        asm("v_cvt_pk_bf16_f32 %0, %1, %2" : "=v"(hu.uw[2]) : "v"(AR[p][1][0]), "v"(AR[p][1][1])); \
        asm("v_cvt_pk_bf16_f32 %0, %1, %2" : "=v"(hu.uw[3]) : "v"(AR[p][1][2]), "v"(AR[p][1][3])); \
        *reinterpret_cast<u16x8*>(reinterpret_cast<char*>(As[buf]) + swz(srow + 32 * p, scol * 16)) = hu.v; } \
    _Pragma("unroll") for (int p = 0; p < 4; ++p) \
        *reinterpret_cast<u16x8*>(reinterpret_cast<char*>(Bs[buf]) + swz(srow + 32 * p, scol * 16)) = BR[p]; \
} while (0)

    auto compute = [&](int buf) {
        #pragma unroll
        for (int c = 0; c < 2; ++c) {
            bf16x8 af[2], bfv[4];
            #pragma unroll
            for (int mf = 0; mf < 2; ++mf)
                af[mf] = *reinterpret_cast<const bf16x8*>(
                    reinterpret_cast<const char*>(As[buf]) + swz(wm + 16 * mf + li, c * 64 + lg * 16));
            #pragma unroll
            for (int nf = 0; nf < 4; ++nf)
                bfv[nf] = *reinterpret_cast<const bf16x8*>(
                    reinterpret_cast<const char*>(Bs[buf]) + swz(wn + 16 * nf + li, c * 64 + lg * 16));
            #pragma unroll
            for (int mf = 0; mf < 2; ++mf)
                #pragma unroll
                for (int nf = 0; nf < 4; ++nf)
                    acc[mf][nf] = __builtin_amdgcn_mfma_f32_16x16x32_bf16(
                        af[mf], bfv[nf], acc[mf][nf], 0, 0, 0);
        }
    };

    PLOAD(0, a0reg, b0reg);
    PLOAD(64, a1reg, b1reg);
    PWRITE(a0reg, b0reg, 0);
    wg_barrier();

    for (int ks = 0; ks < 32; ks += 2) {
        if (ks + 2 < 32) PLOAD((ks + 2) * 64, a0reg, b0reg);
        compute(0);
        PWRITE(a1reg, b1reg, 1);
        wg_barrier();
        if (ks + 3 < 32) PLOAD((ks + 3) * 64, a1reg, b1reg);
        compute(1);
        if (ks + 2 < 32) PWRITE(a0reg, b0reg, 0);
        wg_barrier();
    }

    const int b = m0 >> 12, s0 = m0 & 4095;
    #pragma unroll
    for (int mf = 0; mf < 2; ++mf) {
        #pragma unroll
        for (int nf = 0; nf < 4; ++nf) {
            int col = wn + 16 * nf + li;
            #pragma unroll
            for (int r = 0; r < 4; ++r) {
                int row = m0 + wm + 16 * mf + 4 * lg + r;
                float v = acc[mf][nf][r];
                if (wn == 0) {
                    latent_out[(long)row * NL + col] = v;
                    k_bf[(long)row * NL + col] = f2bf(v);
                    *reinterpret_cast<ushort_t*>(reinterpret_cast<char*>(As[0]) +
                        swz(wm + 16 * mf + 4 * lg + r, col * 2)) = f2bf(v);
                } else {
                    q_bf[(long)row * NL + (col - 64)] = f2bf(v);
                }
            }
        }
    }
    wg_barrier();
    // kt-GEMM: kt[l][s] = latent^T via A = identity fragment.
    union { u16x8 u; bf16x8 v; } iu;
    #pragma unroll
    for (int j = 0; j < 8; ++j)
        iu.u[j] = (lg == (li >> 3) + 2 * (w & 1) && (li & 7) == j)
                      ? (ushort_t)0x3F80 : (ushort_t)0;
    const int ckt = w >> 1;
    f32x4 ktacc[4];
    #pragma unroll
    for (int nf = 0; nf < 4; ++nf) {
        bf16x8 bfv = *reinterpret_cast<const bf16x8*>(
            reinterpret_cast<const char*>(As[0]) + swz(16 * nf + li, ckt * 64 + lg * 16));
        ktacc[nf] = __builtin_amdgcn_mfma_f32_16x16x32_bf16(
            iu.v, bfv, f32x4{0.f, 0.f, 0.f, 0.f}, 0, 0, 0);
    }
    #pragma unroll
    for (int nf = 0; nf < 4; ++nf)
        #pragma unroll
        for (int r = 0; r < 4; ++r)
            kt[(long)(b * 64 + 16 * w + 4 * lg + r) * NS + s0 + 16 * nf + li] =
                f2bf(ktacc[nf][r]);
}

// ---------------------------------------------------------------------------
// attn: causal flash attention in latent space, kv-SPLIT ACROSS WAVES.
// 512 blocks = (b, qt-perm). Chunk = 128 kv; wave w owns kv slice [32w,32w+32)
// and all 64 q (Q fragments in regs). Per-wave split-KV shards (m,l,O~ bf16)
// merged in-block via LDS; Wv projection + transpose-store fused in epilogue.
// LDS kv' permutation: col' = [w1 w0 lg1 lg0 kvb r1 r0] so P stays in regs.
// ---------------------------------------------------------------------------
__global__ __launch_bounds__(256, 2) void attn_kernel(
    const ushort_t* __restrict__ q_bf, const ushort_t* __restrict__ k_bf,
    const ushort_t* __restrict__ kt, const float* __restrict__ Wv,
    float* __restrict__ out)
{
    __shared__ __attribute__((aligned(16))) char smem[65536];
    // main loop: Ks[2] @ 0/16K (128x64 bf16, 128B rows); KTs[2] @ 32K/48K (64x128 bf16, 256B rows)
    // epilogue:  OW bf16 [4][64][64] @ 0 (32K); mw @ 32K; lw @ 33K;
    //            Ms @ 36K (8K); Wvs @ 44K+ (16K); Os f32 [64][132] @ 0 (33K)
    ushort_t* OW = (ushort_t*)smem;
    float* mw = (float*)(smem + 32768);
    float* lw = (float*)(smem + 33792);
    ushort_t* Ms = (ushort_t*)(smem + 36864);
    ushort_t* Wvs = (ushort_t*)(smem + 45056);
    float* Os = (float*)smem;

    const int tid = threadIdx.x;
    const int w = tid >> 6, lane = tid & 63, lg = lane >> 4, li = lane & 15;
    const int l = blockIdx.x;
    const int b = l & 7;
    const int p_ = l >> 3;
    // balanced qt permutation (R5-validated under both XCD dispatch policies)
    const int k_ = p_ >> 1, e_ = p_ & 1, kk = (k_ & 15) * 2;
    const int qt = (k_ >> 4) ? (e_ ? kk + 1 : 63 - kk) : (e_ ? 62 - kk : kk);
    const int Q0 = qt << 6;
    const int nch = (qt >> 1) + 1;       // ceil((qt+1)/2) 128-kv chunks

    // staging thread roles
    const int krow = tid >> 1, khalf = tid & 1;     // K: [128][64]
    const int trow = tid >> 2, tkq = (tid & 3) * 32; // KT: [64][128]

    // Q fragments: ALL 64 q rows per wave. qf[qb][c][j] = Q[Q0+16qb+li][c*32+lg*8+j]
    bf16x8 qf[4][2];
    #pragma unroll
    for (int qb = 0; qb < 4; ++qb)
        #pragma unroll
        for (int c = 0; c < 2; ++c)
            qf[qb][c] = *reinterpret_cast<const bf16x8*>(
                q_bf + ((long)b * NS + Q0 + 16 * qb + li) * NL + c * 32 + lg * 8);

    float m_r[4], l_r[4];
    #pragma unroll
    for (int qb = 0; qb < 4; ++qb) { m_r[qb] = -1.0e30f; l_r[qb] = 0.f; }
    f32x4 oacc[4][4];
    #pragma unroll
    for (int qb = 0; qb < 4; ++qb)
        #pragma unroll
        for (int n = 0; n < 4; ++n) oacc[qb][n] = f32x4{0.f, 0.f, 0.f, 0.f};

    u16x8 k0reg[4], t0reg[4], k1reg[4], t1reg[4];

#define ALOAD(ch, KR, TR) do { \
    const int kv0_ = (ch) * 128; \
    _Pragma("unroll") for (int pp = 0; pp < 4; ++pp) \
        KR[pp] = *reinterpret_cast<const u16x8*>( \
            k_bf + ((long)b * NS + kv0_ + krow) * NL + khalf * 32 + pp * 8); \
    _Pragma("unroll") for (int pp = 0; pp < 4; ++pp) \
        TR[pp] = *reinterpret_cast<const u16x8*>( \
            kt + ((long)b * 64 + trow) * NS + kv0_ + tkq + pp * 8); \
} while (0)

#define AWRITE(KR, TR, buf) do { \
    char* Kb_ = smem + (buf) * 16384; \
    char* Tb_ = smem + 32768 + (buf) * 16384; \
    _Pragma("unroll") for (int pp = 0; pp < 4; ++pp) \
        *reinterpret_cast<u16x8*>(Kb_ + swz(krow, khalf * 64 + pp * 16)) = KR[pp]; \
    _Pragma("unroll") for (int pp = 0; pp < 4; ++pp) { \
        const int kv8 = tkq + pp * 8; \
        const int colp = (kv8 & 0x60) | ((kv8 & 0xC) << 1) | ((kv8 & 0x10) >> 2); \
        const int xo = (trow & 15) << 4; \
        u16x4 lo = {TR[pp][0], TR[pp][1], TR[pp][2], TR[pp][3]}; \
        u16x4 hi = {TR[pp][4], TR[pp][5], TR[pp][6], TR[pp][7]}; \
        *reinterpret_cast<u16x4*>(Tb_ + trow * 256 + ((colp * 2) ^ xo)) = lo; \
        *reinterpret_cast<u16x4*>(Tb_ + trow * 256 + (((colp + 8) * 2) ^ xo)) = hi; \
    } \
} while (0)

    auto compute = [&](int buf, bool diag, int kv0) {
        const char* Kb = smem + buf * 16384;
        const char* Tb = smem + 32768 + buf * 16384;
        f32x4 s[2][4];
        #pragma unroll
        for (int kvb = 0; kvb < 2; ++kvb)
            #pragma unroll
            for (int qb = 0; qb < 4; ++qb) s[kvb][qb] = f32x4{0.f, 0.f, 0.f, 0.f};
        __builtin_amdgcn_s_setprio(1);
        #pragma unroll
        for (int c = 0; c < 2; ++c)
            #pragma unroll
            for (int kvb = 0; kvb < 2; ++kvb) {
                bf16x8 a = *reinterpret_cast<const bf16x8*>(
                    Kb + swz(32 * w + 16 * kvb + li, c * 64 + lg * 16));
                #pragma unroll
                for (int qb = 0; qb < 4; ++qb)
                    s[kvb][qb] = __builtin_amdgcn_mfma_f32_16x16x32_bf16(
                        a, qf[qb][c], s[kvb][qb], 0, 0, 0);
            }
        __builtin_amdgcn_s_setprio(0);
        if (diag) {
            #pragma unroll
            for (int kvb = 0; kvb < 2; ++kvb)
                #pragma unroll
                for (int qb = 0; qb < 4; ++qb)
                    #pragma unroll
                    for (int r = 0; r < 4; ++r) {
                        int kv_g = kv0 + 32 * w + 16 * kvb + 4 * lg + r;
                        int q_g = Q0 + 16 * qb + li;
                        if (kv_g > q_g) s[kvb][qb][r] = -3.0e38f;
                    }
        }
        // per-lane partial maxima per q-column
        float mx[4];
        #pragma unroll
        for (int qb = 0; qb < 4; ++qb) {
            float m0_ = fmaxf(fmaxf(s[0][qb][0], s[0][qb][1]), fmaxf(s[0][qb][2], s[0][qb][3]));
            float m1_ = fmaxf(fmaxf(s[1][qb][0], s[1][qb][1]), fmaxf(s[1][qb][2], s[1][qb][3]));
            mx[qb] = fmaxf(m0_, m1_);
        }
        bool ok = (mx[0] <= m_r[0] + 8.f) && (mx[1] <= m_r[1] + 8.f) &&
                  (mx[2] <= m_r[2] + 8.f) && (mx[3] <= m_r[3] + 8.f);
        if (!__all(ok)) {
            #pragma unroll
            for (int qb = 0; qb < 4; ++qb) {
                float mxf = fmaxf(mx[qb], __shfl_xor(mx[qb], 16));
                mxf = fmaxf(mxf, __shfl_xor(mxf, 32));
                float m_new = fmaxf(m_r[qb], mxf);
                float corr = fast_exp2(m_r[qb] - m_new);
                m_r[qb] = m_new;
                l_r[qb] *= corr;
                float corrO[4];
                #pragma unroll
                for (int r = 0; r < 4; ++r)
                    corrO[r] = __shfl(corr, (lane & 48) | (4 * lg + r));
                #pragma unroll
                for (int n = 0; n < 4; ++n)
                    #pragma unroll
                    for (int r = 0; r < 4; ++r) oacc[qb][n][r] *= corrO[r];
            }
        }
        #pragma unroll
        for (int qb = 0; qb < 4; ++qb) {
            float rs = 0.f;
            #pragma unroll
            for (int kvb = 0; kvb < 2; ++kvb)
                #pragma unroll
                for (int r = 0; r < 4; ++r) {
                    float pv = fast_exp2(s[kvb][qb][r] - m_r[qb]);
                    s[kvb][qb][r] = pv;
                    rs += pv;
                }
            l_r[qb] += rs;
        }
        // PV: B-fragments (kv'-permuted kt tile), one b128 per n
        bf16x8 vb[4];
        #pragma unroll
        for (int n = 0; n < 4; ++n)
            vb[n] = *reinterpret_cast<const bf16x8*>(
                Tb + (16 * n + li) * 256 + ((64 * w + 16 * lg) ^ (li << 4)));
        __builtin_amdgcn_s_setprio(1);
        #pragma unroll
        for (int qb = 0; qb < 4; ++qb) {
            union { unsigned uw[4]; bf16x8 v; } pa;
            asm("v_cvt_pk_bf16_f32 %0, %1, %2" : "=v"(pa.uw[0]) : "v"(s[0][qb][0]), "v"(s[0][qb][1]));
            asm("v_cvt_pk_bf16_f32 %0, %1, %2" : "=v"(pa.uw[1]) : "v"(s[0][qb][2]), "v"(s[0][qb][3]));
            asm("v_cvt_pk_bf16_f32 %0, %1, %2" : "=v"(pa.uw[2]) : "v"(s[1][qb][0]), "v"(s[1][qb][1]));
            asm("v_cvt_pk_bf16_f32 %0, %1, %2" : "=v"(pa.uw[3]) : "v"(s[1][qb][2]), "v"(s[1][qb][3]));
            #pragma unroll
            for (int n = 0; n < 4; ++n)
                oacc[qb][n] = __builtin_amdgcn_mfma_f32_16x16x32_bf16(
                    pa.v, vb[n], oacc[qb][n], 0, 0, 0);
        }
        __builtin_amdgcn_s_setprio(0);
    };

    // depth-2 ping-pong pipeline over 128-kv chunks
    ALOAD(0, k0reg, t0reg);
    if (nch >= 2) ALOAD(1, k1reg, t1reg);
    AWRITE(k0reg, t0reg, 0);
    wg_barrier();
    for (int i = 0; i < nch; i += 2) {
        if (i + 2 < nch) ALOAD(i + 2, k0reg, t0reg);
        compute(0, i == nch - 1, i * 128);
        if (i + 1 < nch) AWRITE(k1reg, t1reg, 1);
        wg_barrier();
        if (i + 1 >= nch) break;
        if (i + 3 < nch) ALOAD(i + 3, k1reg, t1reg);
        compute(1, i + 1 == nch - 1, (i + 1) * 128);
        if (i + 2 < nch) AWRITE(k0reg, t0reg, 0);
        wg_barrier();
    }

    // ---- in-block merge of the 4 wave-shards ----
    #pragma unroll
    for (int qb = 0; qb < 4; ++qb) {
        l_r[qb] += __shfl_xor(l_r[qb], 16);
        l_r[qb] += __shfl_xor(l_r[qb], 32);
    }
    if (lg == 0) {
        #pragma unroll
        for (int qb = 0; qb < 4; ++qb) {
            mw[w * 64 + 16 * qb + li] = m_r[qb];
            lw[w * 64 + 16 * qb + li] = l_r[qb];
        }
    }
    // O~ bf16, dv' = (dv&15)*4 + (dv>>4) permuted layout (vectorized writes)
    #pragma unroll
    for (int qb = 0; qb < 4; ++qb)
        #pragma unroll
        for (int r = 0; r < 4; ++r) {
            union { unsigned uw[2]; u16x4 v; } u;
            asm("v_cvt_pk_bf16_f32 %0, %1, %2" : "=v"(u.uw[0]) : "v"(oacc[qb][0][r]), "v"(oacc[qb][1][r]));
            asm("v_cvt_pk_bf16_f32 %0, %1, %2" : "=v"(u.uw[1]) : "v"(oacc[qb][2][r]), "v"(oacc[qb][3][r]));
            int q = 16 * qb + 4 * lg + r;
            *reinterpret_cast<u16x4*>(OW + (w * 64 + q) * 64 + li * 4) = u.v;
        }
    wg_barrier();

    // merge + Wv staging. thread: q = tid>>2, dv block g*16..
    {
        const int q = tid >> 2, g = tid & 3;
        float m4[4], l4[4];
        #pragma unroll
        for (int ww = 0; ww < 4; ++ww) { m4[ww] = mw[ww * 64 + q]; l4[ww] = lw[ww * 64 + q]; }
        float M = fmaxf(fmaxf(m4[0], m4[1]), fmaxf(m4[2], m4[3]));
        float cw[4], L = 0.f;
        #pragma unroll
        for (int ww = 0; ww < 4; ++ww) { cw[ww] = fast_exp2(m4[ww] - M); L += cw[ww] * l4[ww]; }
        float inv = 1.f / L;
        float merged[16];
        #pragma unroll
        for (int e = 0; e < 16; ++e) {
            float a = 0.f;
            #pragma unroll
            for (int ww = 0; ww < 4; ++ww)
                a += cw[ww] * bf2f(OW[(ww * 64 + q) * 64 + e * 4 + g]);
            merged[e] = a * inv;
        }
        #pragma unroll
        for (int ee = 0; ee < 8; ++ee) {
            unsigned pk;
            asm("v_cvt_pk_bf16_f32 %0, %1, %2" : "=v"(pk) : "v"(merged[2 * ee]), "v"(merged[2 * ee + 1]));
            *reinterpret_cast<unsigned*>(reinterpret_cast<char*>(Ms) + swz(q, g * 32 + 4 * ee)) = pk;
        }
        // stage Wv (f32 -> bf16) -> Wvs: [128 dv][64 l], swizzled
        const int r = tid >> 1, hf = tid & 1;
        const float* wp = Wv + r * 64 + hf * 32;
        #pragma unroll
        for (int qq = 0; qq < 2; ++qq) {
            f32x4 w0 = *reinterpret_cast<const f32x4*>(wp + qq * 16);
            f32x4 w1 = *reinterpret_cast<const f32x4*>(wp + qq * 16 + 4);
            f32x4 w2 = *reinterpret_cast<const f32x4*>(wp + qq * 16 + 8);
            f32x4 w3 = *reinterpret_cast<const f32x4*>(wp + qq * 16 + 12);
            u16x8 h0, h1;
            #pragma unroll
            for (int jj = 0; jj < 4; ++jj) {
                h0[jj] = f2bf(w0[jj]); h0[4 + jj] = f2bf(w1[jj]);
                h1[jj] = f2bf(w2[jj]); h1[4 + jj] = f2bf(w3[jj]);
            }
            *reinterpret_cast<u16x8*>(reinterpret_cast<char*>(Wvs) + swz(r, hf * 64 + qq * 32)) = h0;
            *reinterpret_cast<u16x8*>(reinterpret_cast<char*>(Wvs) + swz(r, hf * 64 + qq * 32 + 16)) = h1;
        }
    }
    wg_barrier();

    // out-GEMM: D[dv][q] = Wv[dv][l] * Om^T[l][q]; wave w owns dv 32w..32w+31
    f32x4 vacc[2][4];
    #pragma unroll
    for (int i = 0; i < 2; ++i)
        #pragma unroll
        for (int j = 0; j < 4; ++j) vacc[i][j] = f32x4{0.f, 0.f, 0.f, 0.f};
    #pragma unroll
    for (int c = 0; c < 2; ++c) {
        bf16x8 af[2], bfv[4];
        #pragma unroll
        for (int mf = 0; mf < 2; ++mf)
            af[mf] = *reinterpret_cast<const bf16x8*>(
                reinterpret_cast<const char*>(Wvs) + swz(32 * w + 16 * mf + li, c * 64 + lg * 16));
        #pragma unroll
        for (int nf = 0; nf < 4; ++nf)
            bfv[nf] = *reinterpret_cast<const bf16x8*>(
                reinterpret_cast<const char*>(Ms) + swz(16 * nf + li, c * 64 + lg * 16));
        #pragma unroll
        for (int mf = 0; mf < 2; ++mf)
            #pragma unroll
            for (int nf = 0; nf < 4; ++nf)
                vacc[mf][nf] = __builtin_amdgcn_mfma_f32_16x16x32_bf16(
                    af[mf], bfv[nf], vacc[mf][nf], 0, 0, 0);
    }
    wg_barrier();
    // transpose-stage Os[q][dv] then coalesced f32x4 global writes
    #pragma unroll
    for (int mf = 0; mf < 2; ++mf)
        #pragma unroll
        for (int nf = 0; nf < 4; ++nf)
            #pragma unroll
            for (int r = 0; r < 4; ++r)
                Os[(16 * nf + li) * 132 + 32 * w + 16 * mf + 4 * lg + r] = vacc[mf][nf][r];
    wg_barrier();
    {
        const int r = tid >> 2, cb = (tid & 3) * 32;
        float* op = out + ((long)b * NS + Q0 + r) * NH + cb;
        const float* sp = Os + r * 132 + cb;
        #pragma unroll
        for (int qq = 0; qq < 8; ++qq)
            *reinterpret_cast<f32x4*>(op + 4 * qq) = *reinterpret_cast<const f32x4*>(sp + 4 * qq);
    }
}

// ---------------------------------------------------------------------------
extern "C" void kernel_launch(void* const* d_in, const int* in_sizes, int n_in,
                              void* d_out, int out_size, void* d_ws, size_t ws_size,
                              hipStream_t stream) {
    const float* x    = (const float*)d_in[0];
    const float* Wdkv = (const float*)d_in[1];
    const float* Wk   = (const float*)d_in[2];
    const float* Wv   = (const float*)d_in[3];
    const float* Wq   = (const float*)d_in[4];

    float* out = (float*)d_out;
    float* latent_out = out + (long)NM * NH;   // output 1 follows output 0

    // workspace (~12.5 MB)
    ushort_t* WcatT = (ushort_t*)d_ws;                 // 512 KB
    ushort_t* q_bf  = WcatT + 128 * NE;                // 4 MB
    ushort_t* k_bf  = q_bf + (long)NM * NL;            // 4 MB
    ushort_t* kt    = k_bf + (long)NM * NL;            // 4 MB (latent^T)

    hipLaunchKernelGGL(prep_kernel, dim3(NE / 256, 4), dim3(256), 0, stream, Wdkv, Wk, Wq, WcatT);
    hipLaunchKernelGGL(proj_kernel, dim3(NM / 64), dim3(256), 0, stream,
                       x, WcatT, latent_out, k_bf, q_bf, kt);
    hipLaunchKernelGGL(attn_kernel, dim3(512), dim3(256), 0, stream,
                       q_bf, k_bf, kt, Wv, out);
}

// Round 9
// 132.573 us; speedup vs baseline: 3.5373x; 1.0128x over previous
//
#include <hip/hip_runtime.h>
#include <hip/hip_bf16.h>

#define NB 8
#define NS 4096
#define NE 2048
#define NL 64
#define NH 128
#define NM (NB*NS)

typedef unsigned short ushort_t;
typedef __attribute__((ext_vector_type(4))) float f32x4;
typedef __attribute__((ext_vector_type(8))) __bf16 bf16x8;
typedef __attribute__((ext_vector_type(8))) unsigned short u16x8;
typedef __attribute__((ext_vector_type(4))) unsigned short u16x4;

// 128^-0.5 * log2(e): folded into absorbed-q weights so attn uses exp2 directly
#define SCALE2 0.1275174537f

__device__ __forceinline__ float fast_exp2(float x) {
    return __builtin_amdgcn_exp2f(x);   // v_exp_f32: D = 2^S0
}

__device__ __forceinline__ unsigned short f2bf(float f) {
    union { float f; unsigned u; } v; v.f = f;
    unsigned u = v.u + 0x7fffu + ((v.u >> 16) & 1u);
    return (unsigned short)(u >> 16);
}

__device__ __forceinline__ float bf2f(ushort_t u) {
    union { unsigned u; float f; } v; v.u = (unsigned)u << 16; return v.f;
}

// XOR swizzle for 128-byte-stride LDS tiles (G4)
__device__ __forceinline__ int swz(int row, int colbyte) {
    return (row * 128 + colbyte) ^ ((row & 7) << 4);
}

// Raw barrier: LDS visibility only — does NOT drain vmcnt (T4).
__device__ __forceinline__ void wg_barrier() {
    asm volatile("s_waitcnt lgkmcnt(0)" ::: "memory");
    __builtin_amdgcn_s_barrier();
    __builtin_amdgcn_sched_barrier(0);
}

// ---------------------------------------------------------------------------
// prep: WcatT[128][2048] bf16.  rows 0..63 = W_dkv, rows 64..127 = absorbed^T * SCALE2
// ---------------------------------------------------------------------------
__global__ __launch_bounds__(256) void prep_kernel(
    const float* __restrict__ Wdkv, const float* __restrict__ Wk,
    const float* __restrict__ Wq, ushort_t* __restrict__ WcatT)
{
    __shared__ float wk[128 * 64];
    const int t = threadIdx.x;
    for (int i = t; i < 128 * 64; i += 256) wk[i] = Wk[i];
    __syncthreads();
    const int e = blockIdx.x * 256 + t;
    const int l0 = blockIdx.y * 16;
    float acc[16];
    #pragma unroll
    for (int l = 0; l < 16; ++l) acc[l] = 0.f;
    for (int h = 0; h < 128; ++h) {
        float q = Wq[h * NE + e];
        #pragma unroll
        for (int l = 0; l < 16; ++l) acc[l] += q * wk[h * 64 + l0 + l];
    }
    for (int l = 0; l < 16; ++l) WcatT[(64 + l0 + l) * NE + e] = f2bf(acc[l] * SCALE2);
    for (int l = 0; l < 16; ++l) WcatT[(l0 + l) * NE + e] = f2bf(Wdkv[(l0 + l) * NE + e]);
}

// ---------------------------------------------------------------------------
// proj: Y[M,128] = x[M,2048] @ WcatT^T.  BM=64,BN=128,BK=64, 4 waves (2x2).
// Depth-2 ping-pong register prefetch + raw barriers.
// Epilogue: latent(f32) + k(bf16) + q(bf16) + kt = latent^T (identity MFMA).
// ---------------------------------------------------------------------------
__global__ __launch_bounds__(256) void proj_kernel(
    const float* __restrict__ x, const ushort_t* __restrict__ WcatT,
    float* __restrict__ latent_out, ushort_t* __restrict__ k_bf,
    ushort_t* __restrict__ q_bf, ushort_t* __restrict__ kt)
{
    __shared__ ushort_t As[2][64 * 64];
    __shared__ ushort_t Bs[2][128 * 64];
    const int tid = threadIdx.x;
    const int w = tid >> 6, lane = tid & 63, lg = lane >> 4, li = lane & 15;
    const int m0 = blockIdx.x * 64;
    const int wm = (w >> 1) * 32, wn = (w & 1) * 64;
    const int srow = tid >> 3, scol = tid & 7;

    f32x4 acc[2][4];
    #pragma unroll
    for (int i = 0; i < 2; ++i)
        #pragma unroll
        for (int j = 0; j < 4; ++j) acc[i][j] = f32x4{0.f, 0.f, 0.f, 0.f};

    f32x4 a0reg[2][2], a1reg[2][2];
    u16x8 b0reg[4], b1reg[4];

#define PLOAD(k0, AR, BR) do { \
    _Pragma("unroll") for (int p = 0; p < 2; ++p) { \
        const float* gp = x + (long)(m0 + srow + 32 * p) * NE + (k0) + scol * 8; \
        AR[p][0] = *reinterpret_cast<const f32x4*>(gp); \
        AR[p][1] = *reinterpret_cast<const f32x4*>(gp + 4); } \
    _Pragma("unroll") for (int p = 0; p < 4; ++p) \
        BR[p] = *reinterpret_cast<const u16x8*>(WcatT + (long)(srow + 32 * p) * NE + (k0) + scol * 8); \
} while (0)

#define PWRITE(AR, BR, buf) do { \
    _Pragma("unroll") for (int p = 0; p < 2; ++p) { \
        union { unsigned uw[4]; u16x8 v; } hu; \
        asm("v_cvt_pk_bf16_f32 %0, %1, %2" : "=v"(hu.uw[0]) : "v"(AR[p][0][0]), "v"(AR[p][0][1])); \
        asm("v_cvt_pk_bf16_f32 %0, %1, %2" : "=v"(hu.uw[1]) : "v"(AR[p][0][2]), "v"(AR[p][0][3])); \
        asm("v_cvt_pk_bf16_f32 %0, %1, %2" : "=v"(hu.uw[2]) : "v"(AR[p][1][0]), "v"(AR[p][1][1])); \
        asm("v_cvt_pk_bf16_f32 %0, %1, %2" : "=v"(hu.uw[3]) : "v"(AR[p][1][2]), "v"(AR[p][1][3])); \
        *reinterpret_cast<u16x8*>(reinterpret_cast<char*>(As[buf]) + swz(srow + 32 * p, scol * 16)) = hu.v; } \
    _Pragma("unroll") for (int p = 0; p < 4; ++p) \
        *reinterpret_cast<u16x8*>(reinterpret_cast<char*>(Bs[buf]) + swz(srow + 32 * p, scol * 16)) = BR[p]; \
} while (0)

    auto compute = [&](int buf) {
        #pragma unroll
        for (int c = 0; c < 2; ++c) {
            bf16x8 af[2], bfv[4];
            #pragma unroll
            for (int mf = 0; mf < 2; ++mf)
                af[mf] = *reinterpret_cast<const bf16x8*>(
                    reinterpret_cast<const char*>(As[buf]) + swz(wm + 16 * mf + li, c * 64 + lg * 16));
            #pragma unroll
            for (int nf = 0; nf < 4; ++nf)
                bfv[nf] = *reinterpret_cast<const bf16x8*>(
                    reinterpret_cast<const char*>(Bs[buf]) + swz(wn + 16 * nf + li, c * 64 + lg * 16));
            #pragma unroll
            for (int mf = 0; mf < 2; ++mf)
                #pragma unroll
                for (int nf = 0; nf < 4; ++nf)
                    acc[mf][nf] = __builtin_amdgcn_mfma_f32_16x16x32_bf16(
                        af[mf], bfv[nf], acc[mf][nf], 0, 0, 0);
        }
    };

    PLOAD(0, a0reg, b0reg);
    PLOAD(64, a1reg, b1reg);
    PWRITE(a0reg, b0reg, 0);
    wg_barrier();

    for (int ks = 0; ks < 32; ks += 2) {
        if (ks + 2 < 32) PLOAD((ks + 2) * 64, a0reg, b0reg);
        compute(0);
        PWRITE(a1reg, b1reg, 1);
        wg_barrier();
        if (ks + 3 < 32) PLOAD((ks + 3) * 64, a1reg, b1reg);
        compute(1);
        if (ks + 2 < 32) PWRITE(a0reg, b0reg, 0);
        wg_barrier();
    }

    const int b = m0 >> 12, s0 = m0 & 4095;
    #pragma unroll
    for (int mf = 0; mf < 2; ++mf) {
        #pragma unroll
        for (int nf = 0; nf < 4; ++nf) {
            int col = wn + 16 * nf + li;
            #pragma unroll
            for (int r = 0; r < 4; ++r) {
                int row = m0 + wm + 16 * mf + 4 * lg + r;
                float v = acc[mf][nf][r];
                if (wn == 0) {
                    latent_out[(long)row * NL + col] = v;
                    k_bf[(long)row * NL + col] = f2bf(v);
                    *reinterpret_cast<ushort_t*>(reinterpret_cast<char*>(As[0]) +
                        swz(wm + 16 * mf + 4 * lg + r, col * 2)) = f2bf(v);
                } else {
                    q_bf[(long)row * NL + (col - 64)] = f2bf(v);
                }
            }
        }
    }
    wg_barrier();
    // kt-GEMM: kt[l][s] = latent^T via A = identity fragment.
    union { u16x8 u; bf16x8 v; } iu;
    #pragma unroll
    for (int j = 0; j < 8; ++j)
        iu.u[j] = (lg == (li >> 3) + 2 * (w & 1) && (li & 7) == j)
                      ? (ushort_t)0x3F80 : (ushort_t)0;
    const int ckt = w >> 1;
    f32x4 ktacc[4];
    #pragma unroll
    for (int nf = 0; nf < 4; ++nf) {
        bf16x8 bfv = *reinterpret_cast<const bf16x8*>(
            reinterpret_cast<const char*>(As[0]) + swz(16 * nf + li, ckt * 64 + lg * 16));
        ktacc[nf] = __builtin_amdgcn_mfma_f32_16x16x32_bf16(
            iu.v, bfv, f32x4{0.f, 0.f, 0.f, 0.f}, 0, 0, 0);
    }
    #pragma unroll
    for (int nf = 0; nf < 4; ++nf)
        #pragma unroll
        for (int r = 0; r < 4; ++r)
            kt[(long)(b * 64 + 16 * w + 4 * lg + r) * NS + s0 + 16 * nf + li] =
                f2bf(ktacc[nf][r]);
}

// ---------------------------------------------------------------------------
// attn: causal flash attention in latent space, kv-SPLIT ACROSS WAVES.
// 512 blocks = (b, qt-perm). Chunk = 128 kv; wave w owns kv slice [32w,32w+32)
// and all 64 q (Q fragments in regs). Per-wave split-KV shards (m,l,O~ bf16)
// merged in-block via LDS; Wv projection + transpose-store fused in epilogue.
// LDS kv' permutation: col' = [w1 w0 lg1 lg0 kvb r1 r0] so P stays in regs.
// ---------------------------------------------------------------------------
__global__ __launch_bounds__(256, 2) void attn_kernel(
    const ushort_t* __restrict__ q_bf, const ushort_t* __restrict__ k_bf,
    const ushort_t* __restrict__ kt, const float* __restrict__ Wv,
    float* __restrict__ out)
{
    __shared__ __attribute__((aligned(16))) char smem[65536];
    // main loop: Ks[2] @ 0/16K (128x64 bf16, 128B rows); KTs[2] @ 32K/48K (64x128 bf16, 256B rows)
    // epilogue:  OW bf16 [4][64][64] @ 0 (32K); mw @ 32K; lw @ 33K;
    //            Ms @ 36K (8K); Wvs @ 44K+ (16K); Os f32 [64][132] @ 0 (33K)
    ushort_t* OW = (ushort_t*)smem;
    float* mw = (float*)(smem + 32768);
    float* lw = (float*)(smem + 33792);
    ushort_t* Ms = (ushort_t*)(smem + 36864);
    ushort_t* Wvs = (ushort_t*)(smem + 45056);
    float* Os = (float*)smem;

    const int tid = threadIdx.x;
    const int w = tid >> 6, lane = tid & 63, lg = lane >> 4, li = lane & 15;
    const int l = blockIdx.x;
    const int b = l & 7;
    const int p_ = l >> 3;
    // balanced qt permutation (R5-validated under both XCD dispatch policies)
    const int k_ = p_ >> 1, e_ = p_ & 1, kk = (k_ & 15) * 2;
    const int qt = (k_ >> 4) ? (e_ ? kk + 1 : 63 - kk) : (e_ ? 62 - kk : kk);
    const int Q0 = qt << 6;
    const int nch = (qt >> 1) + 1;       // ceil((qt+1)/2) 128-kv chunks

    // staging thread roles
    const int krow = tid >> 1, khalf = tid & 1;     // K: [128][64]
    const int trow = tid >> 2, tkq = (tid & 3) * 32; // KT: [64][128]

    // Q fragments: ALL 64 q rows per wave. qf[qb][c][j] = Q[Q0+16qb+li][c*32+lg*8+j]
    bf16x8 qf[4][2];
    #pragma unroll
    for (int qb = 0; qb < 4; ++qb)
        #pragma unroll
        for (int c = 0; c < 2; ++c)
            qf[qb][c] = *reinterpret_cast<const bf16x8*>(
                q_bf + ((long)b * NS + Q0 + 16 * qb + li) * NL + c * 32 + lg * 8);

    float m_r[4], l_r[4];
    #pragma unroll
    for (int qb = 0; qb < 4; ++qb) { m_r[qb] = -1.0e30f; l_r[qb] = 0.f; }
    f32x4 oacc[4][4];
    #pragma unroll
    for (int qb = 0; qb < 4; ++qb)
        #pragma unroll
        for (int n = 0; n < 4; ++n) oacc[qb][n] = f32x4{0.f, 0.f, 0.f, 0.f};

    u16x8 k0reg[4], t0reg[4], k1reg[4], t1reg[4];

#define ALOAD(ch, KR, TR) do { \
    const int kv0_ = (ch) * 128; \
    _Pragma("unroll") for (int pp = 0; pp < 4; ++pp) \
        KR[pp] = *reinterpret_cast<const u16x8*>( \
            k_bf + ((long)b * NS + kv0_ + krow) * NL + khalf * 32 + pp * 8); \
    _Pragma("unroll") for (int pp = 0; pp < 4; ++pp) \
        TR[pp] = *reinterpret_cast<const u16x8*>( \
            kt + ((long)b * 64 + trow) * NS + kv0_ + tkq + pp * 8); \
} while (0)

#define AWRITE(KR, TR, buf) do { \
    char* Kb_ = smem + (buf) * 16384; \
    char* Tb_ = smem + 32768 + (buf) * 16384; \
    _Pragma("unroll") for (int pp = 0; pp < 4; ++pp) \
        *reinterpret_cast<u16x8*>(Kb_ + swz(krow, khalf * 64 + pp * 16)) = KR[pp]; \
    _Pragma("unroll") for (int pp = 0; pp < 4; ++pp) { \
        const int kv8 = tkq + pp * 8; \
        const int colp = (kv8 & 0x60) | ((kv8 & 0xC) << 1) | ((kv8 & 0x10) >> 2); \
        const int xo = (trow & 15) << 4; \
        u16x4 lo = {TR[pp][0], TR[pp][1], TR[pp][2], TR[pp][3]}; \
        u16x4 hi = {TR[pp][4], TR[pp][5], TR[pp][6], TR[pp][7]}; \
        *reinterpret_cast<u16x4*>(Tb_ + trow * 256 + ((colp * 2) ^ xo)) = lo; \
        *reinterpret_cast<u16x4*>(Tb_ + trow * 256 + (((colp + 8) * 2) ^ xo)) = hi; \
    } \
} while (0)

    auto compute = [&](int buf, bool diag, int kv0) {
        const char* Kb = smem + buf * 16384;
        const char* Tb = smem + 32768 + buf * 16384;
        f32x4 s[2][4];
        #pragma unroll
        for (int kvb = 0; kvb < 2; ++kvb)
            #pragma unroll
            for (int qb = 0; qb < 4; ++qb) s[kvb][qb] = f32x4{0.f, 0.f, 0.f, 0.f};
        __builtin_amdgcn_s_setprio(1);
        #pragma unroll
        for (int c = 0; c < 2; ++c)
            #pragma unroll
            for (int kvb = 0; kvb < 2; ++kvb) {
                bf16x8 a = *reinterpret_cast<const bf16x8*>(
                    Kb + swz(32 * w + 16 * kvb + li, c * 64 + lg * 16));
                #pragma unroll
                for (int qb = 0; qb < 4; ++qb)
                    s[kvb][qb] = __builtin_amdgcn_mfma_f32_16x16x32_bf16(
                        a, qf[qb][c], s[kvb][qb], 0, 0, 0);
            }
        __builtin_amdgcn_s_setprio(0);
        if (diag) {
            #pragma unroll
            for (int kvb = 0; kvb < 2; ++kvb)
                #pragma unroll
                for (int qb = 0; qb < 4; ++qb)
                    #pragma unroll
                    for (int r = 0; r < 4; ++r) {
                        int kv_g = kv0 + 32 * w + 16 * kvb + 4 * lg + r;
                        int q_g = Q0 + 16 * qb + li;
                        if (kv_g > q_g) s[kvb][qb][r] = -3.0e38f;
                    }
        }
        // per-lane partial maxima per q-column
        float mx[4];
        #pragma unroll
        for (int qb = 0; qb < 4; ++qb) {
            float m0_ = fmaxf(fmaxf(s[0][qb][0], s[0][qb][1]), fmaxf(s[0][qb][2], s[0][qb][3]));
            float m1_ = fmaxf(fmaxf(s[1][qb][0], s[1][qb][1]), fmaxf(s[1][qb][2], s[1][qb][3]));
            mx[qb] = fmaxf(m0_, m1_);
        }
        bool ok = (mx[0] <= m_r[0] + 8.f) && (mx[1] <= m_r[1] + 8.f) &&
                  (mx[2] <= m_r[2] + 8.f) && (mx[3] <= m_r[3] + 8.f);
        if (!__all(ok)) {
            #pragma unroll
            for (int qb = 0; qb < 4; ++qb) {
                float mxf = fmaxf(mx[qb], __shfl_xor(mx[qb], 16));
                mxf = fmaxf(mxf, __shfl_xor(mxf, 32));
                float m_new = fmaxf(m_r[qb], mxf);
                float corr = fast_exp2(m_r[qb] - m_new);
                m_r[qb] = m_new;
                l_r[qb] *= corr;
                float corrO[4];
                #pragma unroll
                for (int r = 0; r < 4; ++r)
                    corrO[r] = __shfl(corr, (lane & 48) | (4 * lg + r));
                #pragma unroll
                for (int n = 0; n < 4; ++n)
                    #pragma unroll
                    for (int r = 0; r < 4; ++r) oacc[qb][n][r] *= corrO[r];
            }
        }
        #pragma unroll
        for (int qb = 0; qb < 4; ++qb) {
            float rs = 0.f;
            #pragma unroll
            for (int kvb = 0; kvb < 2; ++kvb)
                #pragma unroll
                for (int r = 0; r < 4; ++r) {
                    float pv = fast_exp2(s[kvb][qb][r] - m_r[qb]);
                    s[kvb][qb][r] = pv;
                    rs += pv;
                }
            l_r[qb] += rs;
        }
        // PV: B-fragments (kv'-permuted kt tile), one b128 per n
        bf16x8 vb[4];
        #pragma unroll
        for (int n = 0; n < 4; ++n)
            vb[n] = *reinterpret_cast<const bf16x8*>(
                Tb + (16 * n + li) * 256 + ((64 * w + 16 * lg) ^ (li << 4)));
        __builtin_amdgcn_s_setprio(1);
        #pragma unroll
        for (int qb = 0; qb < 4; ++qb) {
            union { unsigned uw[4]; bf16x8 v; } pa;
            asm("v_cvt_pk_bf16_f32 %0, %1, %2" : "=v"(pa.uw[0]) : "v"(s[0][qb][0]), "v"(s[0][qb][1]));
            asm("v_cvt_pk_bf16_f32 %0, %1, %2" : "=v"(pa.uw[1]) : "v"(s[0][qb][2]), "v"(s[0][qb][3]));
            asm("v_cvt_pk_bf16_f32 %0, %1, %2" : "=v"(pa.uw[2]) : "v"(s[1][qb][0]), "v"(s[1][qb][1]));
            asm("v_cvt_pk_bf16_f32 %0, %1, %2" : "=v"(pa.uw[3]) : "v"(s[1][qb][2]), "v"(s[1][qb][3]));
            #pragma unroll
            for (int n = 0; n < 4; ++n)
                oacc[qb][n] = __builtin_amdgcn_mfma_f32_16x16x32_bf16(
                    pa.v, vb[n], oacc[qb][n], 0, 0, 0);
        }
        __builtin_amdgcn_s_setprio(0);
    };

    // depth-2 ping-pong pipeline over 128-kv chunks
    ALOAD(0, k0reg, t0reg);
    if (nch >= 2) ALOAD(1, k1reg, t1reg);
    AWRITE(k0reg, t0reg, 0);
    wg_barrier();
    for (int i = 0; i < nch; i += 2) {
        if (i + 2 < nch) ALOAD(i + 2, k0reg, t0reg);
        compute(0, i == nch - 1, i * 128);
        if (i + 1 < nch) AWRITE(k1reg, t1reg, 1);
        wg_barrier();
        if (i + 1 >= nch) break;
        if (i + 3 < nch) ALOAD(i + 3, k1reg, t1reg);
        compute(1, i + 1 == nch - 1, (i + 1) * 128);
        if (i + 2 < nch) AWRITE(k0reg, t0reg, 0);
        wg_barrier();
    }

    // ---- in-block merge of the 4 wave-shards ----
    #pragma unroll
    for (int qb = 0; qb < 4; ++qb) {
        l_r[qb] += __shfl_xor(l_r[qb], 16);
        l_r[qb] += __shfl_xor(l_r[qb], 32);
    }
    if (lg == 0) {
        #pragma unroll
        for (int qb = 0; qb < 4; ++qb) {
            mw[w * 64 + 16 * qb + li] = m_r[qb];
            lw[w * 64 + 16 * qb + li] = l_r[qb];
        }
    }
    // O~ bf16, dv' = (dv&15)*4 + (dv>>4) permuted layout (vectorized writes)
    #pragma unroll
    for (int qb = 0; qb < 4; ++qb)
        #pragma unroll
        for (int r = 0; r < 4; ++r) {
            union { unsigned uw[2]; u16x4 v; } u;
            asm("v_cvt_pk_bf16_f32 %0, %1, %2" : "=v"(u.uw[0]) : "v"(oacc[qb][0][r]), "v"(oacc[qb][1][r]));
            asm("v_cvt_pk_bf16_f32 %0, %1, %2" : "=v"(u.uw[1]) : "v"(oacc[qb][2][r]), "v"(oacc[qb][3][r]));
            int q = 16 * qb + 4 * lg + r;
            *reinterpret_cast<u16x4*>(OW + (w * 64 + q) * 64 + li * 4) = u.v;
        }
    wg_barrier();

    // merge + Wv staging. thread: q = tid>>2, dv block g*16..
    {
        const int q = tid >> 2, g = tid & 3;
        float m4[4], l4[4];
        #pragma unroll
        for (int ww = 0; ww < 4; ++ww) { m4[ww] = mw[ww * 64 + q]; l4[ww] = lw[ww * 64 + q]; }
        float M = fmaxf(fmaxf(m4[0], m4[1]), fmaxf(m4[2], m4[3]));
        float cw[4], L = 0.f;
        #pragma unroll
        for (int ww = 0; ww < 4; ++ww) { cw[ww] = fast_exp2(m4[ww] - M); L += cw[ww] * l4[ww]; }
        float inv = 1.f / L;
        float merged[16];
        #pragma unroll
        for (int e = 0; e < 16; ++e) {
            float a = 0.f;
            #pragma unroll
            for (int ww = 0; ww < 4; ++ww)
                a += cw[ww] * bf2f(OW[(ww * 64 + q) * 64 + e * 4 + g]);
            merged[e] = a * inv;
        }
        #pragma unroll
        for (int ee = 0; ee < 8; ++ee) {
            unsigned pk;
            asm("v_cvt_pk_bf16_f32 %0, %1, %2" : "=v"(pk) : "v"(merged[2 * ee]), "v"(merged[2 * ee + 1]));
            *reinterpret_cast<unsigned*>(reinterpret_cast<char*>(Ms) + swz(q, g * 32 + 4 * ee)) = pk;
        }
        // stage Wv (f32 -> bf16) -> Wvs: [128 dv][64 l], swizzled
        const int r = tid >> 1, hf = tid & 1;
        const float* wp = Wv + r * 64 + hf * 32;
        #pragma unroll
        for (int qq = 0; qq < 2; ++qq) {
            f32x4 w0 = *reinterpret_cast<const f32x4*>(wp + qq * 16);
            f32x4 w1 = *reinterpret_cast<const f32x4*>(wp + qq * 16 + 4);
            f32x4 w2 = *reinterpret_cast<const f32x4*>(wp + qq * 16 + 8);
            f32x4 w3 = *reinterpret_cast<const f32x4*>(wp + qq * 16 + 12);
            u16x8 h0, h1;
            #pragma unroll
            for (int jj = 0; jj < 4; ++jj) {
                h0[jj] = f2bf(w0[jj]); h0[4 + jj] = f2bf(w1[jj]);
                h1[jj] = f2bf(w2[jj]); h1[4 + jj] = f2bf(w3[jj]);
            }
            *reinterpret_cast<u16x8*>(reinterpret_cast<char*>(Wvs) + swz(r, hf * 64 + qq * 32)) = h0;
            *reinterpret_cast<u16x8*>(reinterpret_cast<char*>(Wvs) + swz(r, hf * 64 + qq * 32 + 16)) = h1;
        }
    }
    wg_barrier();

    // out-GEMM: D[dv][q] = Wv[dv][l] * Om^T[l][q]; wave w owns dv 32w..32w+31
    f32x4 vacc[2][4];
    #pragma unroll
    for (int i = 0; i < 2; ++i)
        #pragma unroll
        for (int j = 0; j < 4; ++j) vacc[i][j] = f32x4{0.f, 0.f, 0.f, 0.f};
    #pragma unroll
    for (int c = 0; c < 2; ++c) {
        bf16x8 af[2], bfv[4];
        #pragma unroll
        for (int mf = 0; mf < 2; ++mf)
            af[mf] = *reinterpret_cast<const bf16x8*>(
                reinterpret_cast<const char*>(Wvs) + swz(32 * w + 16 * mf + li, c * 64 + lg * 16));
        #pragma unroll
        for (int nf = 0; nf < 4; ++nf)
            bfv[nf] = *reinterpret_cast<const bf16x8*>(
                reinterpret_cast<const char*>(Ms) + swz(16 * nf + li, c * 64 + lg * 16));
        #pragma unroll
        for (int mf = 0; mf < 2; ++mf)
            #pragma unroll
            for (int nf = 0; nf < 4; ++nf)
                vacc[mf][nf] = __builtin_amdgcn_mfma_f32_16x16x32_bf16(
                    af[mf], bfv[nf], vacc[mf][nf], 0, 0, 0);
    }
    wg_barrier();
    // transpose-stage Os[q][dv] then coalesced f32x4 global writes
    #pragma unroll
    for (int mf = 0; mf < 2; ++mf)
        #pragma unroll
        for (int nf = 0; nf < 4; ++nf)
            #pragma unroll
            for (int r = 0; r < 4; ++r)
                Os[(16 * nf + li) * 132 + 32 * w + 16 * mf + 4 * lg + r] = vacc[mf][nf][r];
    wg_barrier();
    {
        const int r = tid >> 2, cb = (tid & 3) * 32;
        float* op = out + ((long)b * NS + Q0 + r) * NH + cb;
        const float* sp = Os + r * 132 + cb;
        #pragma unroll
        for (int qq = 0; qq < 8; ++qq)
            *reinterpret_cast<f32x4*>(op + 4 * qq) = *reinterpret_cast<const f32x4*>(sp + 4 * qq);
    }
}

// ---------------------------------------------------------------------------
extern "C" void kernel_launch(void* const* d_in, const int* in_sizes, int n_in,
                              void* d_out, int out_size, void* d_ws, size_t ws_size,
                              hipStream_t stream) {
    const float* x    = (const float*)d_in[0];
    const float* Wdkv = (const float*)d_in[1];
    const float* Wk   = (const float*)d_in[2];
    const float* Wv   = (const float*)d_in[3];
    const float* Wq   = (const float*)d_in[4];

    float* out = (float*)d_out;
    float* latent_out = out + (long)NM * NH;   // output 1 follows output 0

    // workspace (~12.5 MB)
    ushort_t* WcatT = (ushort_t*)d_ws;                 // 512 KB
    ushort_t* q_bf  = WcatT + 128 * NE;                // 4 MB
    ushort_t* k_bf  = q_bf + (long)NM * NL;            // 4 MB
    ushort_t* kt    = k_bf + (long)NM * NL;            // 4 MB (latent^T)

    hipLaunchKernelGGL(prep_kernel, dim3(NE / 256, 4), dim3(256), 0, stream, Wdkv, Wk, Wq, WcatT);
    hipLaunchKernelGGL(proj_kernel, dim3(NM / 64), dim3(256), 0, stream,
                       x, WcatT, latent_out, k_bf, q_bf, kt);
    hipLaunchKernelGGL(attn_kernel, dim3(512), dim3(256), 0, stream,
                       q_bf, k_bf, kt, Wv, out);
}